// Round 3
// baseline (5626.030 us; speedup 1.0000x reference)
//
#include <hip/hip_runtime.h>
#include <math.h>

#ifndef M_PI
#define M_PI 3.14159265358979323846
#endif

#define BB 4
#define TT 500
#define NSAMP 120000
#define NHARM 32
#define NFFT 256
#define NBIN 129
#define NHOPF 64
#define NFRAMES 1876
#define HID 64
#define MLPD 128
#define FEATD 88

#define R_MAG ((float)(500.0/1876.0))
#define R_UP_F ((float)(500.0/120000.0))

// ---- workspace layout (float offsets) ----
#define OFF_HARML 0
#define OFF_HARMR 64000
#define OFF_AMP   128000
#define OFF_NMAGL 130000
#define OFF_NMAGR 388000
#define OFF_C1    646000            /* 128 floats: RN32(c32*mf32) per (b,k) */
#define OFF_TRUNK 646128
#define OFF_FEAT  (OFF_TRUNK)
#define OFF_H1    (OFF_FEAT+176000)
#define OFF_H2    (OFF_H1+256000)
#define OFF_GI    (OFF_H2+256000)
#define OFF_GOUT  (OFF_GI+384000)
#define OFF_POST  (OFF_GOUT+128000)
/* spec reuses trunk region (trunk dead after k_heads) */
#define OFF_SPECL (OFF_TRUNK)
#define OFF_SPECR (OFF_SPECL+1936032)
#define OFF_FRL   (OFF_SPECR+1936032)
#define OFF_FRR   (OFF_FRL+1921024)
/* total = 8360240 floats = 33.44 MB */

// f32 upsample position/interp chain, bit-exact to numpy float32 elementwise
__device__ __forceinline__ void up_coords(int m, int* i0, int* i1, float* w, float* w1){
  float pos = __fadd_rn(__fmul_rn(__fadd_rn((float)m, 0.5f), R_UP_F), -0.5f);
  pos = fminf(fmaxf(pos, 0.0f), 499.0f);
  int a = (int)pos;
  *i0 = a; *i1 = min(a+1, TT-1);
  float ww = __fsub_rn(pos, (float)a);
  *w = ww; *w1 = __fsub_rn(1.0f, ww);
}
__device__ __forceinline__ float f0_up_elem(const float* __restrict__ f0s, int m){
  int i0,i1; float w,w1;
  up_coords(m,&i0,&i1,&w,&w1);
  return __fadd_rn(__fmul_rn(f0s[i0], w1), __fmul_rn(f0s[i1], w));
}

// ---------------- encoding ----------------
__global__ void k_enc(const float* __restrict__ f0, const float* __restrict__ ldb,
                      const float* __restrict__ vel, float* __restrict__ feat){
  int idx = blockIdx.x*blockDim.x + threadIdx.x;
  if (idx >= BB*TT) return;
  int b = idx / TT;
  float f = f0[idx];
  float gate = (f > 0.0f) ? 1.0f : 0.0f;
  float fs = fmaxf(f, 20.0f);
  float fn = (logf(fs) - (float)2.995732273553991) / (float)5.5214609178622464;
  fn = fminf(fmaxf(fn, 0.0f), 1.0f);
  float ln = fminf(fmaxf((ldb[idx] + 80.0f) / 80.0f, 0.0f), 1.0f);
  float vn = fminf(fmaxf(vel[b] / 7.0f, 0.0f), 1.0f);
  float* o = feat + idx*FEATD;
  #pragma unroll 4
  for (int i=1;i<=32;i++){
    float ang = (float)M_PI * (float)i * fn;
    o[2*i-2] = sinf(ang)*gate;
    o[2*i-1] = cosf(ang)*gate;
  }
  #pragma unroll
  for (int i=1;i<=8;i++){
    float ang = (float)M_PI * (float)i * ln;
    o[64+2*i-2] = sinf(ang);
    o[64+2*i-1] = cosf(ang);
  }
  #pragma unroll
  for (int i=1;i<=4;i++){
    float ang = (float)M_PI * (float)i * vn;
    o[80+2*i-2] = sinf(ang);
    o[80+2*i-1] = cosf(ang);
  }
}

// ---------------- generic matmul: out = act(in @ W^T + b) ----------------
template<int ACT>
__global__ void k_mm(const float* __restrict__ in, const float* __restrict__ W,
                     const float* __restrict__ bias, float* __restrict__ out,
                     int R, int C, int IN){
  int idx = blockIdx.x*blockDim.x + threadIdx.x;
  if (idx >= R*C) return;
  int r = idx / C, c = idx - r*C;
  const float* ip = in + r*IN;
  const float* wp = W + c*IN;
  float acc = bias[c];
  #pragma unroll 8
  for (int i=0;i<IN;i++) acc = fmaf(ip[i], wp[i], acc);
  if (ACT==1) acc = fmaxf(acc, 0.0f);
  out[idx] = acc;
}

// ---------------- GRU recurrence (gi precomputed) ----------------
__global__ __launch_bounds__(64,1) void k_gru(const float* __restrict__ gi,
    const float* __restrict__ Whh, const float* __restrict__ bhh,
    float* __restrict__ gout){
  int b = blockIdx.x;
  int j = threadIdx.x;
  float wr[64], wz[64], wn[64];
  #pragma unroll
  for (int i=0;i<16;i++){
    float4 a = *(const float4*)(Whh + (j)*64     + i*4);
    float4 c = *(const float4*)(Whh + (64+j)*64  + i*4);
    float4 d = *(const float4*)(Whh + (128+j)*64 + i*4);
    wr[4*i]=a.x; wr[4*i+1]=a.y; wr[4*i+2]=a.z; wr[4*i+3]=a.w;
    wz[4*i]=c.x; wz[4*i+1]=c.y; wz[4*i+2]=c.z; wz[4*i+3]=c.w;
    wn[4*i]=d.x; wn[4*i+1]=d.y; wn[4*i+2]=d.z; wn[4*i+3]=d.w;
  }
  float br = bhh[j], bz = bhh[64+j], bn = bhh[128+j];
  __shared__ __align__(16) float hs[2][64];
  hs[0][j] = 0.0f;
  float hreg = 0.0f;
  __syncthreads();
  const float* gp = gi + (size_t)b*TT*192;
  float* op = gout + (size_t)b*TT*64;
  for (int t=0;t<TT;t++){
    float gr = gp[t*192 + j], gz = gp[t*192 + 64 + j], gn = gp[t*192 + 128 + j];
    const float* hp = hs[t&1];
    float ar=0.f, az=0.f, an=0.f;
    #pragma unroll
    for (int i=0;i<16;i++){
      float4 h4 = *(const float4*)(hp + 4*i);
      ar = fmaf(wr[4*i],  h4.x, ar); az = fmaf(wz[4*i],  h4.x, az); an = fmaf(wn[4*i],  h4.x, an);
      ar = fmaf(wr[4*i+1],h4.y, ar); az = fmaf(wz[4*i+1],h4.y, az); an = fmaf(wn[4*i+1],h4.y, an);
      ar = fmaf(wr[4*i+2],h4.z, ar); az = fmaf(wz[4*i+2],h4.z, az); an = fmaf(wn[4*i+2],h4.z, an);
      ar = fmaf(wr[4*i+3],h4.w, ar); az = fmaf(wz[4*i+3],h4.w, az); an = fmaf(wn[4*i+3],h4.w, an);
    }
    float r = 1.0f/(1.0f+expf(-(gr+ar+br)));
    float z = 1.0f/(1.0f+expf(-(gz+az+bz)));
    float n = tanhf(gn + r*(an+bn));
    float hnew = (1.0f - z)*n + z*hreg;
    op[t*64 + j] = hnew;
    hs[(t+1)&1][j] = hnew;
    hreg = hnew;
    __syncthreads();
  }
}

// ---------------- heads ----------------
__global__ void k_heads(const float* __restrict__ post,
  const float* __restrict__ WhL, const float* __restrict__ bhL,
  const float* __restrict__ WhR, const float* __restrict__ bhR,
  const float* __restrict__ Wam, const float* __restrict__ bam,
  const float* __restrict__ WnL, const float* __restrict__ bnL,
  const float* __restrict__ WnR, const float* __restrict__ bnR,
  float* __restrict__ harmL, float* __restrict__ harmR, float* __restrict__ amp,
  float* __restrict__ nmagL, float* __restrict__ nmagR){
  int idx = blockIdx.x*blockDim.x + threadIdx.x;
  if (idx >= BB*TT*323) return;
  int r = idx / 323, c = idx - r*323;
  const float* W; const float* bb; float* o; int oc, ow; bool sp=false;
  if (c < 32)      { W=WhL; bb=bhL; o=harmL; oc=c;     ow=32; }
  else if (c < 64) { W=WhR; bb=bhR; o=harmR; oc=c-32;  ow=32; }
  else if (c == 64){ W=Wam; bb=bam; o=amp;   oc=0;     ow=1; sp=true; }
  else if (c < 194){ W=WnL; bb=bnL; o=nmagL; oc=c-65;  ow=129; }
  else             { W=WnR; bb=bnR; o=nmagR; oc=c-194; ow=129; }
  const float* ip = post + r*MLPD;
  const float* wp = W + oc*MLPD;
  float acc = bb[oc];
  #pragma unroll 8
  for (int i=0;i<MLPD;i++) acc = fmaf(ip[i], wp[i], acc);
  float v;
  if (sp) v = fmaxf(acc, 0.0f) + log1pf(expf(-fabsf(acc)));   // softplus (stable)
  else    v = 1.0f/(1.0f+expf(-acc));                          // sigmoid
  o[r*ow + oc] = v;
}

// ---------------- numpy-exact pairwise mean of inst_freq per (b,k) ----------------
// Replicates numpy pairwise_sum_FLOAT: n<8 sequential; n<=128 block with 8
// accumulators + ((r0+r1)+(r2+r3))+((r4+r5)+(r6+r7)); else split n2=n/2-n/2%8.
__device__ float np_block_sum(const float* __restrict__ f0s, int off, int n, float kf){
  float r[8];
  if (n < 8){
    float res = 0.0f;
    for (int i=0;i<n;i++)
      res = __fadd_rn(res, __fmul_rn(f0_up_elem(f0s, off+i), kf));
    return res;
  }
  #pragma unroll
  for (int j=0;j<8;j++) r[j] = __fmul_rn(f0_up_elem(f0s, off+j), kf);
  int lim = n - (n & 7);
  int i = 8;
  for (; i<lim; i+=8){
    #pragma unroll
    for (int j=0;j<8;j++)
      r[j] = __fadd_rn(r[j], __fmul_rn(f0_up_elem(f0s, off+i+j), kf));
  }
  float res = __fadd_rn(__fadd_rn(__fadd_rn(r[0],r[1]), __fadd_rn(r[2],r[3])),
                        __fadd_rn(__fadd_rn(r[4],r[5]), __fadd_rn(r[6],r[7])));
  for (; i<n; i++)
    res = __fadd_rn(res, __fmul_rn(f0_up_elem(f0s, off+i), kf));
  return res;
}

__global__ __launch_bounds__(256) void k_meanf0_np(const float* __restrict__ f0, float* __restrict__ ws){
  int b = blockIdx.x;
  int k = blockIdx.y;           // 0..31 -> harmonic k+1
  float kf = (float)(k+1);
  int tid = threadIdx.x;
  __shared__ float f0s[TT];
  __shared__ float leaf[2048];
  for (int i=tid;i<TT;i+=256) f0s[i] = f0[b*TT+i];
  __syncthreads();
  // Phase A: enumerate leaves (same DFS on all threads), round-robin compute
  {
    int offst[40], nst[40];
    int sp=0; offst[0]=0; nst[0]=NSAMP; sp=1;
    int leafIdx=0;
    while (sp>0){
      sp--;
      int off=offst[sp], n=nst[sp];
      while (n>128){
        int n2=n/2; n2 -= (n2 & 7);
        offst[sp]=off+n2; nst[sp]=n-n2; sp++;   // push right
        n=n2;                                    // descend left
      }
      if ((leafIdx & 255) == tid) leaf[leafIdx] = np_block_sum(f0s, off, n, kf);
      leafIdx++;
    }
  }
  __syncthreads();
  // Phase B: thread 0 replays recursion, combining leaf sums in exact order
  if (tid==0){
    int ns2[40]; signed char st2[40]; float lv2[40];
    int sp2=0; ns2[0]=NSAMP; st2[0]=0; sp2=1;
    float retv=0.0f; int li=0;
    while (sp2>0){
      int top=sp2-1;
      int n=ns2[top];
      if (n<=128){ retv = leaf[li++]; sp2--; continue; }
      if (st2[top]==0){ int n2=n/2; n2-=(n2&7); st2[top]=1; ns2[sp2]=n2; st2[sp2]=0; sp2++; }
      else if (st2[top]==1){ lv2[top]=retv; st2[top]=2; int n2=n/2; n2-=(n2&7); ns2[sp2]=n-n2; st2[sp2]=0; sp2++; }
      else { retv = __fadd_rn(lv2[top], retv); sp2--; }
    }
    float mf = __fdiv_rn(retv, 120000.0f);                    // np.mean: sum/n in f32
    float c1 = __fmul_rn((float)(2.0*M_PI/48000.0), mf);      // RN32(c32*mf32)
    ws[OFF_C1 + b*32 + k] = c1;
  }
}

// ---------------- forward STFT (windowed frames -> rfft bins) ----------------
__global__ __launch_bounds__(64) void k_stft(const float* __restrict__ nL, const float* __restrict__ nR,
                                             float* __restrict__ ws){
  int fr = blockIdx.x;           // b*NFRAMES + f
  int ch = blockIdx.y;
  int b = fr / NFRAMES, f = fr - b*NFRAMES;
  const float* x = (ch ? nR : nL) + (size_t)b*NSAMP;
  float* spec = ws + (ch ? OFF_SPECR : OFF_SPECL) + (size_t)fr*258;
  int j = threadIdx.x;
  __shared__ float frs[256];
  __shared__ float2 tw[256];
  for (int n=j;n<256;n+=64){
    double a = (2.0*M_PI/256.0)*(double)n;
    tw[n] = make_float2((float)cos(a), (float)sin(a));
    int xi = f*NHOPF + n - 128;
    xi = xi < 0 ? -xi : xi;
    xi = xi >= NSAMP ? 2*(NSAMP-1)-xi : xi;
    float w = (float)(0.5 - 0.5*cos(a));
    frs[n] = x[xi]*w;
  }
  __syncthreads();
  float re0=0.f, im0=0.f, re1=0.f, im1=0.f;
  int m0 = 0;                       // (j*n) & 255, incrementally
  #pragma unroll 4
  for (int n=0;n<256;n++){
    float fv = frs[n];
    int m1 = (m0 + ((n&3)<<6)) & 255;
    float2 t0 = tw[m0], t1 = tw[m1];
    re0 = fmaf(fv, t0.x, re0); im0 = fmaf(-fv, t0.y, im0);
    re1 = fmaf(fv, t1.x, re1); im1 = fmaf(-fv, t1.y, im1);
    m0 = (m0 + j) & 255;
  }
  // Nyquist bin 128: sum of (-1)^n * frs[n]; n = j + 64q -> sign = (-1)^j
  float p = frs[j] + frs[j+64] + frs[j+128] + frs[j+192];
  p = (j & 1) ? -p : p;
  for (int o=32;o>0;o>>=1) p += __shfl_down(p, o, 64);
  spec[2*j]   = re0; spec[2*j+1]   = im0;
  spec[2*(j+64)] = re1; spec[2*(j+64)+1] = im1;
  if (j==0){ spec[256] = p; spec[257] = 0.0f; }
}

// ---------------- mag filter + irfft + window ----------------
__global__ __launch_bounds__(256) void k_istft(float* __restrict__ ws){
  int fr = blockIdx.x;
  int ch = blockIdx.y;
  int b = fr / NFRAMES, f = fr - b*NFRAMES;
  const float* spec = ws + (ch ? OFF_SPECR : OFF_SPECL) + (size_t)fr*258;
  const float* nmag = ws + (ch ? OFF_NMAGR : OFF_NMAGL) + (size_t)b*TT*NBIN;
  float* outfr = ws + (ch ? OFF_FRR : OFF_FRL) + (size_t)fr*256;
  int t = threadIdx.x;
  __shared__ float2 tw[256];
  __shared__ float2 mx[NBIN];
  double a = (2.0*M_PI/256.0)*(double)t;
  float cz = (float)cos(a), sz = (float)sin(a);
  tw[t] = make_float2(cz, sz);
  if (t < NBIN){
    float pos = ((float)f + 0.5f) * R_MAG - 0.5f;
    pos = fminf(fmaxf(pos, 0.0f), 499.0f);
    int i0 = (int)pos, i1 = min(i0+1, TT-1);
    float w = pos - (float)i0;
    float mg = nmag[i0*NBIN + t]*(1.0f-w) + nmag[i1*NBIN + t]*w;
    mx[t] = make_float2(spec[2*t]*mg, spec[2*t+1]*mg);
  }
  __syncthreads();
  float acc0 = mx[0].x + ((t&1) ? -mx[128].x : mx[128].x);
  float acc = 0.0f;
  int mi = t;                      // (k*t)&255 for k=1
  #pragma unroll 4
  for (int k=1;k<128;k++){
    float2 v = mx[k];
    float2 tk = tw[mi];
    acc = fmaf(v.x, tk.x, acc);
    acc = fmaf(-v.y, tk.y, acc);
    mi = (mi + t) & 255;
  }
  float y = (acc0 + 2.0f*acc) * (1.0f/256.0f);
  float win = 0.5f - 0.5f*cz;
  outfr[t] = y*win;
}

// ---------------- final: harmonic synth + OLA gather ----------------
__global__ __launch_bounds__(256) void k_out(const float* __restrict__ f0,
    const float* __restrict__ ws, float* __restrict__ out){
  __shared__ float win2[256];
  __shared__ float c1s[BB*32];
  {
    int t = threadIdx.x;
    double a = (2.0*M_PI/256.0)*(double)t;
    float w = (float)(0.5 - 0.5*cos(a));
    win2[t] = w*w;
    if (t < BB*32) c1s[t] = ws[OFF_C1 + t];
  }
  __syncthreads();
  int idx = blockIdx.x*256 + threadIdx.x;
  if (idx >= BB*2*NSAMP) return;
  int m = idx % NSAMP;
  int bc = idx / NSAMP;
  int ch = bc & 1, b = bc >> 1;
  // f32 interp chain (bit-exact to numpy f32 elementwise)
  int i0,i1; float w,w1;
  up_coords(m,&i0,&i1,&w,&w1);
  const float* f0b = f0 + b*TT;
  float f0u = __fadd_rn(__fmul_rn(f0b[i0], w1), __fmul_rn(f0b[i1], w));
  const float* am = ws + OFF_AMP + b*TT;
  float oa = __fadd_rn(__fmul_rn(am[i0], w1), __fmul_rn(am[i1], w));
  const float* ha = ws + (ch ? OFF_HARMR : OFF_HARML) + (size_t)b*TT*NHARM;
  float tm = (float)m;
  float hsum = 0.0f;
  for (int k=1;k<=NHARM;k++){
    float instf = __fmul_rn(f0u, (float)k);          // RN32(f0_up*k), exact mask
    if (instf < 21600.0f){
      float a0 = ha[i0*NHARM + (k-1)], a1 = ha[i1*NHARM + (k-1)];
      float ak = __fadd_rn(__fmul_rn(a0, w1), __fmul_rn(a1, w));
      float ph = __fmul_rn(c1s[b*32 + (k-1)], tm);   // RN32(c1*t): exact f32 phase
      double rev = (double)ph * 0.15915494309189535; // /(2pi) in f64
      double fr2 = rev - floor(rev);
      float rad = (float)((fr2 - (fr2 >= 0.5 ? 1.0 : 0.0)) * 6.283185307179586);
      float s = sinf(rad);                            // sin(exact f32 phase)
      hsum = __fadd_rn(hsum, __fmul_rn(ak, s));
    }
  }
  float harm = __fmul_rn(hsum, oa);
  // noise OLA gather
  int p = m + 128;
  int fhi = min(p >> 6, NFRAMES-1);
  int flo = max((p - 192) >> 6, 0);
  const float* frb = ws + (ch ? OFF_FRR : OFF_FRL) + (size_t)b*NFRAMES*256;
  float nacc = 0.0f, wsum = 0.0f;
  for (int f=flo; f<=fhi; f++){
    int n = p - f*NHOPF;
    nacc += frb[f*256 + n];
    wsum += win2[n];
  }
  float noise = nacc / fmaxf(wsum, 1e-11f);
  out[idx] = __fadd_rn(harm, noise);
}

extern "C" void kernel_launch(void* const* d_in, const int* in_sizes, int n_in,
                              void* d_out, int out_size, void* d_ws, size_t ws_size,
                              hipStream_t stream){
  const float* f0  = (const float*)d_in[0];
  const float* ldb = (const float*)d_in[1];
  const float* vel = (const float*)d_in[2];
  const float* nL  = (const float*)d_in[3];
  const float* nR  = (const float*)d_in[4];
  const float* Wp1 = (const float*)d_in[5];
  const float* bp1 = (const float*)d_in[6];
  const float* Wp2 = (const float*)d_in[7];
  const float* bp2 = (const float*)d_in[8];
  const float* Wih = (const float*)d_in[9];
  const float* Whh = (const float*)d_in[10];
  const float* bih = (const float*)d_in[11];
  const float* bhh = (const float*)d_in[12];
  const float* Wpo = (const float*)d_in[13];
  const float* bpo = (const float*)d_in[14];
  const float* WhL = (const float*)d_in[15];
  const float* bhL = (const float*)d_in[16];
  const float* WhR = (const float*)d_in[17];
  const float* bhR = (const float*)d_in[18];
  const float* Wam = (const float*)d_in[19];
  const float* bam = (const float*)d_in[20];
  const float* WnL = (const float*)d_in[21];
  const float* bnL = (const float*)d_in[22];
  const float* WnR = (const float*)d_in[23];
  const float* bnR = (const float*)d_in[24];
  float* ws = (float*)d_ws;
  float* out = (float*)d_out;

  k_enc<<<(BB*TT+255)/256, 256, 0, stream>>>(f0, ldb, vel, ws+OFF_FEAT);
  k_mm<1><<<(BB*TT*128+255)/256, 256, 0, stream>>>(ws+OFF_FEAT, Wp1, bp1, ws+OFF_H1, BB*TT, 128, FEATD);
  k_mm<1><<<(BB*TT*128+255)/256, 256, 0, stream>>>(ws+OFF_H1, Wp2, bp2, ws+OFF_H2, BB*TT, 128, 128);
  k_mm<0><<<(BB*TT*192+255)/256, 256, 0, stream>>>(ws+OFF_H2, Wih, bih, ws+OFF_GI, BB*TT, 192, 128);
  k_gru<<<BB, 64, 0, stream>>>(ws+OFF_GI, Whh, bhh, ws+OFF_GOUT);
  k_mm<1><<<(BB*TT*128+255)/256, 256, 0, stream>>>(ws+OFF_GOUT, Wpo, bpo, ws+OFF_POST, BB*TT, 128, HID);
  k_heads<<<(BB*TT*323+255)/256, 256, 0, stream>>>(ws+OFF_POST, WhL,bhL, WhR,bhR, Wam,bam, WnL,bnL, WnR,bnR,
      ws+OFF_HARML, ws+OFF_HARMR, ws+OFF_AMP, ws+OFF_NMAGL, ws+OFF_NMAGR);
  dim3 gmf(BB, 32);
  k_meanf0_np<<<gmf, 256, 0, stream>>>(f0, ws);
  dim3 gs(BB*NFRAMES, 2);
  k_stft<<<gs, 64, 0, stream>>>(nL, nR, ws);
  k_istft<<<gs, 256, 0, stream>>>(ws);
  k_out<<<(BB*2*NSAMP+255)/256, 256, 0, stream>>>(f0, ws, out);
}

// Round 4
// 721.652 us; speedup vs baseline: 7.7960x; 7.7960x over previous
//
#include <hip/hip_runtime.h>
#include <math.h>

#ifndef M_PI
#define M_PI 3.14159265358979323846
#endif

#define BB 4
#define TT 500
#define NSAMP 120000
#define NHARM 32
#define NFFT 256
#define NBIN 129
#define NHOPF 64
#define NFRAMES 1876
#define HID 64
#define MLPD 128
#define FEATD 88

#define R_MAG ((float)(500.0/1876.0))
#define R_UP_F ((float)(500.0/120000.0))

// ---- workspace layout (float offsets) ----
#define OFF_HARML 0
#define OFF_HARMR 64000
#define OFF_AMP   128000
#define OFF_NMAGL 130000
#define OFF_NMAGR 388000
#define OFF_C1    646000            /* 128 floats: RN32(c32*mf32) per (b,k) */
#define OFF_TRUNK 646128
#define OFF_FEAT  (OFF_TRUNK)
#define OFF_H1    (OFF_FEAT+176000)
#define OFF_H2    (OFF_H1+256000)
#define OFF_GI    (OFF_H2+256000)
#define OFF_GOUT  (OFF_GI+384000)
#define OFF_POST  (OFF_GOUT+128000)
/* spec reuses trunk region (trunk dead after k_heads) */
#define OFF_SPECL (OFF_TRUNK)
#define OFF_SPECR (OFF_SPECL+1936032)
#define OFF_FRL   (OFF_SPECR+1936032)
#define OFF_FRR   (OFF_FRL+1921024)
/* total = 8360240 floats = 33.44 MB */

// f32 upsample position/interp chain, bit-exact to numpy float32 elementwise
__device__ __forceinline__ void up_coords(int m, int* i0, int* i1, float* w, float* w1){
  float pos = __fadd_rn(__fmul_rn(__fadd_rn((float)m, 0.5f), R_UP_F), -0.5f);
  pos = fminf(fmaxf(pos, 0.0f), 499.0f);
  int a = (int)pos;
  *i0 = a; *i1 = min(a+1, TT-1);
  float ww = __fsub_rn(pos, (float)a);
  *w = ww; *w1 = __fsub_rn(1.0f, ww);
}
__device__ __forceinline__ float f0_up_elem(const float* __restrict__ f0s, int m){
  int i0,i1; float w,w1;
  up_coords(m,&i0,&i1,&w,&w1);
  return __fadd_rn(__fmul_rn(f0s[i0], w1), __fmul_rn(f0s[i1], w));
}

// ---------------- encoding ----------------
__global__ void k_enc(const float* __restrict__ f0, const float* __restrict__ ldb,
                      const float* __restrict__ vel, float* __restrict__ feat){
  int idx = blockIdx.x*blockDim.x + threadIdx.x;
  if (idx >= BB*TT) return;
  int b = idx / TT;
  float f = f0[idx];
  float gate = (f > 0.0f) ? 1.0f : 0.0f;
  float fs = fmaxf(f, 20.0f);
  float fn = (logf(fs) - (float)2.995732273553991) / (float)5.5214609178622464;
  fn = fminf(fmaxf(fn, 0.0f), 1.0f);
  float ln = fminf(fmaxf((ldb[idx] + 80.0f) / 80.0f, 0.0f), 1.0f);
  float vn = fminf(fmaxf(vel[b] / 7.0f, 0.0f), 1.0f);
  float* o = feat + idx*FEATD;
  #pragma unroll 4
  for (int i=1;i<=32;i++){
    float ang = (float)M_PI * (float)i * fn;
    o[2*i-2] = sinf(ang)*gate;
    o[2*i-1] = cosf(ang)*gate;
  }
  #pragma unroll
  for (int i=1;i<=8;i++){
    float ang = (float)M_PI * (float)i * ln;
    o[64+2*i-2] = sinf(ang);
    o[64+2*i-1] = cosf(ang);
  }
  #pragma unroll
  for (int i=1;i<=4;i++){
    float ang = (float)M_PI * (float)i * vn;
    o[80+2*i-2] = sinf(ang);
    o[80+2*i-1] = cosf(ang);
  }
}

// ---------------- generic matmul: out = act(in @ W^T + b) ----------------
template<int ACT>
__global__ void k_mm(const float* __restrict__ in, const float* __restrict__ W,
                     const float* __restrict__ bias, float* __restrict__ out,
                     int R, int C, int IN){
  int idx = blockIdx.x*blockDim.x + threadIdx.x;
  if (idx >= R*C) return;
  int r = idx / C, c = idx - r*C;
  const float* ip = in + r*IN;
  const float* wp = W + c*IN;
  float acc = bias[c];
  #pragma unroll 8
  for (int i=0;i<IN;i++) acc = fmaf(ip[i], wp[i], acc);
  if (ACT==1) acc = fmaxf(acc, 0.0f);
  out[idx] = acc;
}

// ---------------- GRU recurrence (gi precomputed) ----------------
__global__ __launch_bounds__(64,1) void k_gru(const float* __restrict__ gi,
    const float* __restrict__ Whh, const float* __restrict__ bhh,
    float* __restrict__ gout){
  int b = blockIdx.x;
  int j = threadIdx.x;
  float wr[64], wz[64], wn[64];
  #pragma unroll
  for (int i=0;i<16;i++){
    float4 a = *(const float4*)(Whh + (j)*64     + i*4);
    float4 c = *(const float4*)(Whh + (64+j)*64  + i*4);
    float4 d = *(const float4*)(Whh + (128+j)*64 + i*4);
    wr[4*i]=a.x; wr[4*i+1]=a.y; wr[4*i+2]=a.z; wr[4*i+3]=a.w;
    wz[4*i]=c.x; wz[4*i+1]=c.y; wz[4*i+2]=c.z; wz[4*i+3]=c.w;
    wn[4*i]=d.x; wn[4*i+1]=d.y; wn[4*i+2]=d.z; wn[4*i+3]=d.w;
  }
  float br = bhh[j], bz = bhh[64+j], bn = bhh[128+j];
  __shared__ __align__(16) float hs[2][64];
  hs[0][j] = 0.0f;
  float hreg = 0.0f;
  __syncthreads();
  const float* gp = gi + (size_t)b*TT*192;
  float* op = gout + (size_t)b*TT*64;
  for (int t=0;t<TT;t++){
    float gr = gp[t*192 + j], gz = gp[t*192 + 64 + j], gn = gp[t*192 + 128 + j];
    const float* hp = hs[t&1];
    float ar=0.f, az=0.f, an=0.f;
    #pragma unroll
    for (int i=0;i<16;i++){
      float4 h4 = *(const float4*)(hp + 4*i);
      ar = fmaf(wr[4*i],  h4.x, ar); az = fmaf(wz[4*i],  h4.x, az); an = fmaf(wn[4*i],  h4.x, an);
      ar = fmaf(wr[4*i+1],h4.y, ar); az = fmaf(wz[4*i+1],h4.y, az); an = fmaf(wn[4*i+1],h4.y, an);
      ar = fmaf(wr[4*i+2],h4.z, ar); az = fmaf(wz[4*i+2],h4.z, az); an = fmaf(wn[4*i+2],h4.z, an);
      ar = fmaf(wr[4*i+3],h4.w, ar); az = fmaf(wz[4*i+3],h4.w, az); an = fmaf(wn[4*i+3],h4.w, an);
    }
    float r = 1.0f/(1.0f+expf(-(gr+ar+br)));
    float z = 1.0f/(1.0f+expf(-(gz+az+bz)));
    float n = tanhf(gn + r*(an+bn));
    float hnew = (1.0f - z)*n + z*hreg;
    op[t*64 + j] = hnew;
    hs[(t+1)&1][j] = hnew;
    hreg = hnew;
    __syncthreads();
  }
}

// ---------------- heads ----------------
__global__ void k_heads(const float* __restrict__ post,
  const float* __restrict__ WhL, const float* __restrict__ bhL,
  const float* __restrict__ WhR, const float* __restrict__ bhR,
  const float* __restrict__ Wam, const float* __restrict__ bam,
  const float* __restrict__ WnL, const float* __restrict__ bnL,
  const float* __restrict__ WnR, const float* __restrict__ bnR,
  float* __restrict__ harmL, float* __restrict__ harmR, float* __restrict__ amp,
  float* __restrict__ nmagL, float* __restrict__ nmagR){
  int idx = blockIdx.x*blockDim.x + threadIdx.x;
  if (idx >= BB*TT*323) return;
  int r = idx / 323, c = idx - r*323;
  const float* W; const float* bb; float* o; int oc, ow; bool sp=false;
  if (c < 32)      { W=WhL; bb=bhL; o=harmL; oc=c;     ow=32; }
  else if (c < 64) { W=WhR; bb=bhR; o=harmR; oc=c-32;  ow=32; }
  else if (c == 64){ W=Wam; bb=bam; o=amp;   oc=0;     ow=1; sp=true; }
  else if (c < 194){ W=WnL; bb=bnL; o=nmagL; oc=c-65;  ow=129; }
  else             { W=WnR; bb=bnR; o=nmagR; oc=c-194; ow=129; }
  const float* ip = post + r*MLPD;
  const float* wp = W + oc*MLPD;
  float acc = bb[oc];
  #pragma unroll 8
  for (int i=0;i<MLPD;i++) acc = fmaf(ip[i], wp[i], acc);
  float v;
  if (sp) v = fmaxf(acc, 0.0f) + log1pf(expf(-fabsf(acc)));   // softplus (stable)
  else    v = 1.0f/(1.0f+expf(-acc));                          // sigmoid
  o[r*ow + oc] = v;
}

// ---------------- numpy-exact pairwise mean of inst_freq per (b,k) ----------------
// numpy pairwise_sum_FLOAT on n=120000 forms a PERFECT depth-10 binary tree:
// every path of splits n2=n/2-(n/2)%8 reaches n<=128 exactly at depth 10
// (sizes: 120000,60000,30000,15000,{7496,7504},{3744,3752},{1872,1880},
// {936,944},{468,472},{232,236,240},{112..124}). So: 1024 leaves, and the
// recursive combine == pairwise-adjacent tree reduction. Leaf (off,n) is a
// 10-step register-only bit-walk; all stack arrays eliminated (scratch-free).
__device__ float np_block_sum(const float* __restrict__ f0s, int off, int n, float kf){
  float r[8];
  #pragma unroll
  for (int j=0;j<8;j++) r[j] = __fmul_rn(f0_up_elem(f0s, off+j), kf);
  int lim = n - (n & 7);
  int i = 8;
  for (; i<lim; i+=8){
    #pragma unroll
    for (int j=0;j<8;j++)
      r[j] = __fadd_rn(r[j], __fmul_rn(f0_up_elem(f0s, off+i+j), kf));
  }
  float res = __fadd_rn(__fadd_rn(__fadd_rn(r[0],r[1]), __fadd_rn(r[2],r[3])),
                        __fadd_rn(__fadd_rn(r[4],r[5]), __fadd_rn(r[6],r[7])));
  for (; i<n; i++)
    res = __fadd_rn(res, __fmul_rn(f0_up_elem(f0s, off+i), kf));
  return res;
}

__global__ __launch_bounds__(256) void k_meanf0_np(const float* __restrict__ f0, float* __restrict__ ws){
  int b = blockIdx.x;
  int k = blockIdx.y;           // 0..31 -> harmonic k+1
  float kf = (float)(k+1);
  int tid = threadIdx.x;
  __shared__ float f0s[TT];
  __shared__ float red[256];
  for (int i=tid;i<TT;i+=256) f0s[i] = f0[b*TT+i];
  __syncthreads();
  // 4 adjacent leaves per thread; combine = depth-8 subtree ((l0+l1)+(l2+l3))
  float lv[4];
  #pragma unroll
  for (int q=0;q<4;q++){
    int leafIdx = tid*4 + q;
    int off = 0, n = NSAMP;
    #pragma unroll
    for (int lvl=9; lvl>=0; --lvl){
      int n2 = (n>>1); n2 -= (n2 & 7);
      if ((leafIdx >> lvl) & 1){ off += n2; n -= n2; } else { n = n2; }
    }
    lv[q] = np_block_sum(f0s, off, n, kf);
  }
  red[tid] = __fadd_rn(__fadd_rn(lv[0],lv[1]), __fadd_rn(lv[2],lv[3]));
  __syncthreads();
  // 8-level pairwise-adjacent LDS reduction (exact recursion order)
  for (int cnt=256; cnt>1; cnt>>=1){
    float v = 0.0f;
    int half = cnt>>1;
    if (tid < half) v = __fadd_rn(red[2*tid], red[2*tid+1]);
    __syncthreads();
    if (tid < half) red[tid] = v;
    __syncthreads();
  }
  if (tid==0){
    float mf = __fdiv_rn(red[0], 120000.0f);                  // np.mean: sum/n in f32
    float c1 = __fmul_rn((float)(2.0*M_PI/48000.0), mf);      // RN32(c32*mf32)
    ws[OFF_C1 + b*32 + k] = c1;
  }
}

// ---------------- forward STFT (windowed frames -> rfft bins) ----------------
__global__ __launch_bounds__(64) void k_stft(const float* __restrict__ nL, const float* __restrict__ nR,
                                             float* __restrict__ ws){
  int fr = blockIdx.x;           // b*NFRAMES + f
  int ch = blockIdx.y;
  int b = fr / NFRAMES, f = fr - b*NFRAMES;
  const float* x = (ch ? nR : nL) + (size_t)b*NSAMP;
  float* spec = ws + (ch ? OFF_SPECR : OFF_SPECL) + (size_t)fr*258;
  int j = threadIdx.x;
  __shared__ float frs[256];
  __shared__ float2 tw[256];
  for (int n=j;n<256;n+=64){
    double a = (2.0*M_PI/256.0)*(double)n;
    tw[n] = make_float2((float)cos(a), (float)sin(a));
    int xi = f*NHOPF + n - 128;
    xi = xi < 0 ? -xi : xi;
    xi = xi >= NSAMP ? 2*(NSAMP-1)-xi : xi;
    float w = (float)(0.5 - 0.5*cos(a));
    frs[n] = x[xi]*w;
  }
  __syncthreads();
  float re0=0.f, im0=0.f, re1=0.f, im1=0.f;
  int m0 = 0;                       // (j*n) & 255, incrementally
  #pragma unroll 4
  for (int n=0;n<256;n++){
    float fv = frs[n];
    int m1 = (m0 + ((n&3)<<6)) & 255;
    float2 t0 = tw[m0], t1 = tw[m1];
    re0 = fmaf(fv, t0.x, re0); im0 = fmaf(-fv, t0.y, im0);
    re1 = fmaf(fv, t1.x, re1); im1 = fmaf(-fv, t1.y, im1);
    m0 = (m0 + j) & 255;
  }
  // Nyquist bin 128: sum of (-1)^n * frs[n]; n = j + 64q -> sign = (-1)^j
  float p = frs[j] + frs[j+64] + frs[j+128] + frs[j+192];
  p = (j & 1) ? -p : p;
  for (int o=32;o>0;o>>=1) p += __shfl_down(p, o, 64);
  spec[2*j]   = re0; spec[2*j+1]   = im0;
  spec[2*(j+64)] = re1; spec[2*(j+64)+1] = im1;
  if (j==0){ spec[256] = p; spec[257] = 0.0f; }
}

// ---------------- mag filter + irfft + window ----------------
__global__ __launch_bounds__(256) void k_istft(float* __restrict__ ws){
  int fr = blockIdx.x;
  int ch = blockIdx.y;
  int b = fr / NFRAMES, f = fr - b*NFRAMES;
  const float* spec = ws + (ch ? OFF_SPECR : OFF_SPECL) + (size_t)fr*258;
  const float* nmag = ws + (ch ? OFF_NMAGR : OFF_NMAGL) + (size_t)b*TT*NBIN;
  float* outfr = ws + (ch ? OFF_FRR : OFF_FRL) + (size_t)fr*256;
  int t = threadIdx.x;
  __shared__ float2 tw[256];
  __shared__ float2 mx[NBIN];
  double a = (2.0*M_PI/256.0)*(double)t;
  float cz = (float)cos(a), sz = (float)sin(a);
  tw[t] = make_float2(cz, sz);
  if (t < NBIN){
    float pos = ((float)f + 0.5f) * R_MAG - 0.5f;
    pos = fminf(fmaxf(pos, 0.0f), 499.0f);
    int i0 = (int)pos, i1 = min(i0+1, TT-1);
    float w = pos - (float)i0;
    float mg = nmag[i0*NBIN + t]*(1.0f-w) + nmag[i1*NBIN + t]*w;
    mx[t] = make_float2(spec[2*t]*mg, spec[2*t+1]*mg);
  }
  __syncthreads();
  float acc0 = mx[0].x + ((t&1) ? -mx[128].x : mx[128].x);
  float acc = 0.0f;
  int mi = t;                      // (k*t)&255 for k=1
  #pragma unroll 4
  for (int k=1;k<128;k++){
    float2 v = mx[k];
    float2 tk = tw[mi];
    acc = fmaf(v.x, tk.x, acc);
    acc = fmaf(-v.y, tk.y, acc);
    mi = (mi + t) & 255;
  }
  float y = (acc0 + 2.0f*acc) * (1.0f/256.0f);
  float win = 0.5f - 0.5f*cz;
  outfr[t] = y*win;
}

// ---------------- final: harmonic synth + OLA gather ----------------
__global__ __launch_bounds__(256) void k_out(const float* __restrict__ f0,
    const float* __restrict__ ws, float* __restrict__ out){
  __shared__ float win2[256];
  __shared__ float c1s[BB*32];
  {
    int t = threadIdx.x;
    double a = (2.0*M_PI/256.0)*(double)t;
    float w = (float)(0.5 - 0.5*cos(a));
    win2[t] = w*w;
    if (t < BB*32) c1s[t] = ws[OFF_C1 + t];
  }
  __syncthreads();
  int idx = blockIdx.x*256 + threadIdx.x;
  if (idx >= BB*2*NSAMP) return;
  int m = idx % NSAMP;
  int bc = idx / NSAMP;
  int ch = bc & 1, b = bc >> 1;
  // f32 interp chain (bit-exact to numpy f32 elementwise)
  int i0,i1; float w,w1;
  up_coords(m,&i0,&i1,&w,&w1);
  const float* f0b = f0 + b*TT;
  float f0u = __fadd_rn(__fmul_rn(f0b[i0], w1), __fmul_rn(f0b[i1], w));
  const float* am = ws + OFF_AMP + b*TT;
  float oa = __fadd_rn(__fmul_rn(am[i0], w1), __fmul_rn(am[i1], w));
  const float* ha = ws + (ch ? OFF_HARMR : OFF_HARML) + (size_t)b*TT*NHARM;
  float tm = (float)m;
  float hsum = 0.0f;
  for (int k=1;k<=NHARM;k++){
    float instf = __fmul_rn(f0u, (float)k);          // RN32(f0_up*k), exact mask
    if (instf < 21600.0f){
      float a0 = ha[i0*NHARM + (k-1)], a1 = ha[i1*NHARM + (k-1)];
      float ak = __fadd_rn(__fmul_rn(a0, w1), __fmul_rn(a1, w));
      float ph = __fmul_rn(c1s[b*32 + (k-1)], tm);   // RN32(c1*t): exact f32 phase
      double rev = (double)ph * 0.15915494309189535; // /(2pi) in f64
      double fr2 = rev - floor(rev);
      float rad = (float)((fr2 - (fr2 >= 0.5 ? 1.0 : 0.0)) * 6.283185307179586);
      float s = sinf(rad);                            // sin(exact f32 phase)
      hsum = __fadd_rn(hsum, __fmul_rn(ak, s));
    }
  }
  float harm = __fmul_rn(hsum, oa);
  // noise OLA gather
  int p = m + 128;
  int fhi = min(p >> 6, NFRAMES-1);
  int flo = max((p - 192) >> 6, 0);
  const float* frb = ws + (ch ? OFF_FRR : OFF_FRL) + (size_t)b*NFRAMES*256;
  float nacc = 0.0f, wsum = 0.0f;
  for (int f=flo; f<=fhi; f++){
    int n = p - f*NHOPF;
    nacc += frb[f*256 + n];
    wsum += win2[n];
  }
  float noise = nacc / fmaxf(wsum, 1e-11f);
  out[idx] = __fadd_rn(harm, noise);
}

extern "C" void kernel_launch(void* const* d_in, const int* in_sizes, int n_in,
                              void* d_out, int out_size, void* d_ws, size_t ws_size,
                              hipStream_t stream){
  const float* f0  = (const float*)d_in[0];
  const float* ldb = (const float*)d_in[1];
  const float* vel = (const float*)d_in[2];
  const float* nL  = (const float*)d_in[3];
  const float* nR  = (const float*)d_in[4];
  const float* Wp1 = (const float*)d_in[5];
  const float* bp1 = (const float*)d_in[6];
  const float* Wp2 = (const float*)d_in[7];
  const float* bp2 = (const float*)d_in[8];
  const float* Wih = (const float*)d_in[9];
  const float* Whh = (const float*)d_in[10];
  const float* bih = (const float*)d_in[11];
  const float* bhh = (const float*)d_in[12];
  const float* Wpo = (const float*)d_in[13];
  const float* bpo = (const float*)d_in[14];
  const float* WhL = (const float*)d_in[15];
  const float* bhL = (const float*)d_in[16];
  const float* WhR = (const float*)d_in[17];
  const float* bhR = (const float*)d_in[18];
  const float* Wam = (const float*)d_in[19];
  const float* bam = (const float*)d_in[20];
  const float* WnL = (const float*)d_in[21];
  const float* bnL = (const float*)d_in[22];
  const float* WnR = (const float*)d_in[23];
  const float* bnR = (const float*)d_in[24];
  float* ws = (float*)d_ws;
  float* out = (float*)d_out;

  k_enc<<<(BB*TT+255)/256, 256, 0, stream>>>(f0, ldb, vel, ws+OFF_FEAT);
  k_mm<1><<<(BB*TT*128+255)/256, 256, 0, stream>>>(ws+OFF_FEAT, Wp1, bp1, ws+OFF_H1, BB*TT, 128, FEATD);
  k_mm<1><<<(BB*TT*128+255)/256, 256, 0, stream>>>(ws+OFF_H1, Wp2, bp2, ws+OFF_H2, BB*TT, 128, 128);
  k_mm<0><<<(BB*TT*192+255)/256, 256, 0, stream>>>(ws+OFF_H2, Wih, bih, ws+OFF_GI, BB*TT, 192, 128);
  k_gru<<<BB, 64, 0, stream>>>(ws+OFF_GI, Whh, bhh, ws+OFF_GOUT);
  k_mm<1><<<(BB*TT*128+255)/256, 256, 0, stream>>>(ws+OFF_GOUT, Wpo, bpo, ws+OFF_POST, BB*TT, 128, HID);
  k_heads<<<(BB*TT*323+255)/256, 256, 0, stream>>>(ws+OFF_POST, WhL,bhL, WhR,bhR, Wam,bam, WnL,bnL, WnR,bnR,
      ws+OFF_HARML, ws+OFF_HARMR, ws+OFF_AMP, ws+OFF_NMAGL, ws+OFF_NMAGR);
  dim3 gmf(BB, 32);
  k_meanf0_np<<<gmf, 256, 0, stream>>>(f0, ws);
  dim3 gs(BB*NFRAMES, 2);
  k_stft<<<gs, 64, 0, stream>>>(nL, nR, ws);
  k_istft<<<gs, 256, 0, stream>>>(ws);
  k_out<<<(BB*2*NSAMP+255)/256, 256, 0, stream>>>(f0, ws, out);
}

// Round 5
// 695.413 us; speedup vs baseline: 8.0902x; 1.0377x over previous
//
#include <hip/hip_runtime.h>
#include <math.h>

#ifndef M_PI
#define M_PI 3.14159265358979323846
#endif

#define BB 4
#define TT 500
#define NSAMP 120000
#define NHARM 32
#define NFFT 256
#define NBIN 129
#define NHOPF 64
#define NFRAMES 1876
#define HID 64
#define MLPD 128
#define FEATD 88

#define R_MAG ((float)(500.0/1876.0))
#define R_UP_F ((float)(500.0/120000.0))

// ---- workspace layout (float offsets) ----
#define OFF_HARML 0
#define OFF_HARMR 64000
#define OFF_AMP   128000
#define OFF_NMAGL 130000
#define OFF_NMAGR 388000
#define OFF_C1    646000            /* 128 floats: RN32(c32*mf32) per (b,k) */
#define OFF_TRUNK 646128
#define OFF_FEAT  (OFF_TRUNK)
#define OFF_H1    (OFF_FEAT+176000)
#define OFF_H2    (OFF_H1+256000)
#define OFF_GI    (OFF_H2+256000)
#define OFF_GOUT  (OFF_GI+384000)
#define OFF_POST  (OFF_GOUT+128000)
/* spec reuses trunk region (trunk dead after k_heads) */
#define OFF_SPECL (OFF_TRUNK)
#define OFF_SPECR (OFF_SPECL+1936032)
#define OFF_FRL   (OFF_SPECR+1936032)
#define OFF_FRR   (OFF_FRL+1921024)
/* total = 8360240 floats = 33.44 MB */

// f32 upsample position/interp chain, bit-exact to numpy float32 elementwise
__device__ __forceinline__ void up_coords(int m, int* i0, int* i1, float* w, float* w1){
  float pos = __fadd_rn(__fmul_rn(__fadd_rn((float)m, 0.5f), R_UP_F), -0.5f);
  pos = fminf(fmaxf(pos, 0.0f), 499.0f);
  int a = (int)pos;
  *i0 = a; *i1 = min(a+1, TT-1);
  float ww = __fsub_rn(pos, (float)a);
  *w = ww; *w1 = __fsub_rn(1.0f, ww);
}
__device__ __forceinline__ float f0_up_elem(const float* __restrict__ f0s, int m){
  int i0,i1; float w,w1;
  up_coords(m,&i0,&i1,&w,&w1);
  return __fadd_rn(__fmul_rn(f0s[i0], w1), __fmul_rn(f0s[i1], w));
}

// ---------------- encoding ----------------
__global__ void k_enc(const float* __restrict__ f0, const float* __restrict__ ldb,
                      const float* __restrict__ vel, float* __restrict__ feat){
  int idx = blockIdx.x*blockDim.x + threadIdx.x;
  if (idx >= BB*TT) return;
  int b = idx / TT;
  float f = f0[idx];
  float gate = (f > 0.0f) ? 1.0f : 0.0f;
  float fs = fmaxf(f, 20.0f);
  float fn = (logf(fs) - (float)2.995732273553991) / (float)5.5214609178622464;
  fn = fminf(fmaxf(fn, 0.0f), 1.0f);
  float ln = fminf(fmaxf((ldb[idx] + 80.0f) / 80.0f, 0.0f), 1.0f);
  float vn = fminf(fmaxf(vel[b] / 7.0f, 0.0f), 1.0f);
  float* o = feat + idx*FEATD;
  #pragma unroll 4
  for (int i=1;i<=32;i++){
    float ang = (float)M_PI * (float)i * fn;
    o[2*i-2] = sinf(ang)*gate;
    o[2*i-1] = cosf(ang)*gate;
  }
  #pragma unroll
  for (int i=1;i<=8;i++){
    float ang = (float)M_PI * (float)i * ln;
    o[64+2*i-2] = sinf(ang);
    o[64+2*i-1] = cosf(ang);
  }
  #pragma unroll
  for (int i=1;i<=4;i++){
    float ang = (float)M_PI * (float)i * vn;
    o[80+2*i-2] = sinf(ang);
    o[80+2*i-1] = cosf(ang);
  }
}

// ---------------- generic matmul: out = act(in @ W^T + b) ----------------
template<int ACT>
__global__ void k_mm(const float* __restrict__ in, const float* __restrict__ W,
                     const float* __restrict__ bias, float* __restrict__ out,
                     int R, int C, int IN){
  int idx = blockIdx.x*blockDim.x + threadIdx.x;
  if (idx >= R*C) return;
  int r = idx / C, c = idx - r*C;
  const float* ip = in + r*IN;
  const float* wp = W + c*IN;
  float acc = bias[c];
  #pragma unroll 8
  for (int i=0;i<IN;i++) acc = fmaf(ip[i], wp[i], acc);
  if (ACT==1) acc = fmaxf(acc, 0.0f);
  out[idx] = acc;
}

// ---------------- GRU recurrence (gi precomputed) ----------------
// Single wave per batch. h broadcast via v_readlane (h[i] is wave-uniform ->
// lives in SGPRs, zero VGPR cost); weights stay in VGPRs (192/lane); no LDS,
// no barriers (so prefetched gi loads stay in flight across the whole step).
__global__ __launch_bounds__(64,1) void k_gru(const float* __restrict__ gi,
    const float* __restrict__ Whh, const float* __restrict__ bhh,
    float* __restrict__ gout){
  int b = blockIdx.x;
  int j = threadIdx.x;
  float wr[64], wz[64], wn[64];
  #pragma unroll
  for (int i=0;i<16;i++){
    float4 a = *(const float4*)(Whh + (j)*64     + i*4);
    float4 c = *(const float4*)(Whh + (64+j)*64  + i*4);
    float4 d = *(const float4*)(Whh + (128+j)*64 + i*4);
    wr[4*i]=a.x; wr[4*i+1]=a.y; wr[4*i+2]=a.z; wr[4*i+3]=a.w;
    wz[4*i]=c.x; wz[4*i+1]=c.y; wz[4*i+2]=c.z; wz[4*i+3]=c.w;
    wn[4*i]=d.x; wn[4*i+1]=d.y; wn[4*i+2]=d.z; wn[4*i+3]=d.w;
  }
  float br = bhh[j], bz = bhh[64+j], bn = bhh[128+j];
  const float* gp = gi + (size_t)b*TT*192 + j;
  float* op = gout + (size_t)b*TT*64 + j;
  float hreg = 0.0f;
  float gr = gp[0], gz = gp[64], gn = gp[128];
  for (int t=0;t<TT;t++){
    // prefetch next step's gate inputs (independent of recurrence)
    int tn = min(t+1, TT-1);
    float gr2 = gp[tn*192], gz2 = gp[tn*192+64], gn2 = gp[tn*192+128];
    float ar=0.f, az=0.f, an=0.f;
    #pragma unroll
    for (int i=0;i<64;i++){
      float hi = __uint_as_float(__builtin_amdgcn_readlane(__float_as_uint(hreg), i));
      ar = fmaf(wr[i], hi, ar);
      az = fmaf(wz[i], hi, az);
      an = fmaf(wn[i], hi, an);
    }
    float r = 1.0f/(1.0f+expf(-(gr+ar+br)));
    float z = 1.0f/(1.0f+expf(-(gz+az+bz)));
    float n = tanhf(gn + r*(an+bn));
    hreg = (1.0f - z)*n + z*hreg;
    op[t*64] = hreg;
    gr=gr2; gz=gz2; gn=gn2;
  }
}

// ---------------- heads ----------------
__global__ void k_heads(const float* __restrict__ post,
  const float* __restrict__ WhL, const float* __restrict__ bhL,
  const float* __restrict__ WhR, const float* __restrict__ bhR,
  const float* __restrict__ Wam, const float* __restrict__ bam,
  const float* __restrict__ WnL, const float* __restrict__ bnL,
  const float* __restrict__ WnR, const float* __restrict__ bnR,
  float* __restrict__ harmL, float* __restrict__ harmR, float* __restrict__ amp,
  float* __restrict__ nmagL, float* __restrict__ nmagR){
  int idx = blockIdx.x*blockDim.x + threadIdx.x;
  if (idx >= BB*TT*323) return;
  int r = idx / 323, c = idx - r*323;
  const float* W; const float* bb; float* o; int oc, ow; bool sp=false;
  if (c < 32)      { W=WhL; bb=bhL; o=harmL; oc=c;     ow=32; }
  else if (c < 64) { W=WhR; bb=bhR; o=harmR; oc=c-32;  ow=32; }
  else if (c == 64){ W=Wam; bb=bam; o=amp;   oc=0;     ow=1; sp=true; }
  else if (c < 194){ W=WnL; bb=bnL; o=nmagL; oc=c-65;  ow=129; }
  else             { W=WnR; bb=bnR; o=nmagR; oc=c-194; ow=129; }
  const float* ip = post + r*MLPD;
  const float* wp = W + oc*MLPD;
  float acc = bb[oc];
  #pragma unroll 8
  for (int i=0;i<MLPD;i++) acc = fmaf(ip[i], wp[i], acc);
  float v;
  if (sp) v = fmaxf(acc, 0.0f) + log1pf(expf(-fabsf(acc)));   // softplus (stable)
  else    v = 1.0f/(1.0f+expf(-acc));                          // sigmoid
  o[r*ow + oc] = v;
}

// ---------------- numpy-exact pairwise mean of inst_freq per (b,k) ----------------
// numpy pairwise_sum_FLOAT on n=120000 forms a PERFECT depth-10 binary tree:
// 1024 leaves (n<=128) all at depth 10; combine == pairwise-adjacent tree.
__device__ float np_block_sum(const float* __restrict__ f0s, int off, int n, float kf){
  float r[8];
  #pragma unroll
  for (int j=0;j<8;j++) r[j] = __fmul_rn(f0_up_elem(f0s, off+j), kf);
  int lim = n - (n & 7);
  int i = 8;
  for (; i<lim; i+=8){
    #pragma unroll
    for (int j=0;j<8;j++)
      r[j] = __fadd_rn(r[j], __fmul_rn(f0_up_elem(f0s, off+i+j), kf));
  }
  float res = __fadd_rn(__fadd_rn(__fadd_rn(r[0],r[1]), __fadd_rn(r[2],r[3])),
                        __fadd_rn(__fadd_rn(r[4],r[5]), __fadd_rn(r[6],r[7])));
  for (; i<n; i++)
    res = __fadd_rn(res, __fmul_rn(f0_up_elem(f0s, off+i), kf));
  return res;
}

__global__ __launch_bounds__(256) void k_meanf0_np(const float* __restrict__ f0, float* __restrict__ ws){
  int b = blockIdx.x;
  int k = blockIdx.y;           // 0..31 -> harmonic k+1
  float kf = (float)(k+1);
  int tid = threadIdx.x;
  __shared__ float f0s[TT];
  __shared__ float red[256];
  for (int i=tid;i<TT;i+=256) f0s[i] = f0[b*TT+i];
  __syncthreads();
  // 4 adjacent leaves per thread; combine = depth-8 subtree ((l0+l1)+(l2+l3))
  float lv[4];
  #pragma unroll
  for (int q=0;q<4;q++){
    int leafIdx = tid*4 + q;
    int off = 0, n = NSAMP;
    #pragma unroll
    for (int lvl=9; lvl>=0; --lvl){
      int n2 = (n>>1); n2 -= (n2 & 7);
      if ((leafIdx >> lvl) & 1){ off += n2; n -= n2; } else { n = n2; }
    }
    lv[q] = np_block_sum(f0s, off, n, kf);
  }
  red[tid] = __fadd_rn(__fadd_rn(lv[0],lv[1]), __fadd_rn(lv[2],lv[3]));
  __syncthreads();
  // 8-level pairwise-adjacent LDS reduction (exact recursion order)
  for (int cnt=256; cnt>1; cnt>>=1){
    float v = 0.0f;
    int half = cnt>>1;
    if (tid < half) v = __fadd_rn(red[2*tid], red[2*tid+1]);
    __syncthreads();
    if (tid < half) red[tid] = v;
    __syncthreads();
  }
  if (tid==0){
    float mf = __fdiv_rn(red[0], 120000.0f);                  // np.mean: sum/n in f32
    float c1 = __fmul_rn((float)(2.0*M_PI/48000.0), mf);      // RN32(c32*mf32)
    ws[OFF_C1 + b*32 + k] = c1;
  }
}

// ---------------- forward STFT (windowed frames -> rfft bins) ----------------
__global__ __launch_bounds__(64) void k_stft(const float* __restrict__ nL, const float* __restrict__ nR,
                                             float* __restrict__ ws){
  int fr = blockIdx.x;           // b*NFRAMES + f
  int ch = blockIdx.y;
  int b = fr / NFRAMES, f = fr - b*NFRAMES;
  const float* x = (ch ? nR : nL) + (size_t)b*NSAMP;
  float* spec = ws + (ch ? OFF_SPECR : OFF_SPECL) + (size_t)fr*258;
  int j = threadIdx.x;
  __shared__ float frs[256];
  __shared__ float2 tw[256];
  for (int n=j;n<256;n+=64){
    double a = (2.0*M_PI/256.0)*(double)n;
    tw[n] = make_float2((float)cos(a), (float)sin(a));
    int xi = f*NHOPF + n - 128;
    xi = xi < 0 ? -xi : xi;
    xi = xi >= NSAMP ? 2*(NSAMP-1)-xi : xi;
    float w = (float)(0.5 - 0.5*cos(a));
    frs[n] = x[xi]*w;
  }
  __syncthreads();
  float re0=0.f, im0=0.f, re1=0.f, im1=0.f;
  int m0 = 0;                       // (j*n) & 255, incrementally
  #pragma unroll 4
  for (int n=0;n<256;n++){
    float fv = frs[n];
    int m1 = (m0 + ((n&3)<<6)) & 255;
    float2 t0 = tw[m0], t1 = tw[m1];
    re0 = fmaf(fv, t0.x, re0); im0 = fmaf(-fv, t0.y, im0);
    re1 = fmaf(fv, t1.x, re1); im1 = fmaf(-fv, t1.y, im1);
    m0 = (m0 + j) & 255;
  }
  // Nyquist bin 128: sum of (-1)^n * frs[n]; n = j + 64q -> sign = (-1)^j
  float p = frs[j] + frs[j+64] + frs[j+128] + frs[j+192];
  p = (j & 1) ? -p : p;
  for (int o=32;o>0;o>>=1) p += __shfl_down(p, o, 64);
  spec[2*j]   = re0; spec[2*j+1]   = im0;
  spec[2*(j+64)] = re1; spec[2*(j+64)+1] = im1;
  if (j==0){ spec[256] = p; spec[257] = 0.0f; }
}

// ---------------- mag filter + irfft + window ----------------
__global__ __launch_bounds__(256) void k_istft(float* __restrict__ ws){
  int fr = blockIdx.x;
  int ch = blockIdx.y;
  int b = fr / NFRAMES, f = fr - b*NFRAMES;
  const float* spec = ws + (ch ? OFF_SPECR : OFF_SPECL) + (size_t)fr*258;
  const float* nmag = ws + (ch ? OFF_NMAGR : OFF_NMAGL) + (size_t)b*TT*NBIN;
  float* outfr = ws + (ch ? OFF_FRR : OFF_FRL) + (size_t)fr*256;
  int t = threadIdx.x;
  __shared__ float2 tw[256];
  __shared__ float2 mx[NBIN];
  double a = (2.0*M_PI/256.0)*(double)t;
  float cz = (float)cos(a), sz = (float)sin(a);
  tw[t] = make_float2(cz, sz);
  if (t < NBIN){
    float pos = ((float)f + 0.5f) * R_MAG - 0.5f;
    pos = fminf(fmaxf(pos, 0.0f), 499.0f);
    int i0 = (int)pos, i1 = min(i0+1, TT-1);
    float w = pos - (float)i0;
    float mg = nmag[i0*NBIN + t]*(1.0f-w) + nmag[i1*NBIN + t]*w;
    mx[t] = make_float2(spec[2*t]*mg, spec[2*t+1]*mg);
  }
  __syncthreads();
  float acc0 = mx[0].x + ((t&1) ? -mx[128].x : mx[128].x);
  float acc = 0.0f;
  int mi = t;                      // (k*t)&255 for k=1
  #pragma unroll 4
  for (int k=1;k<128;k++){
    float2 v = mx[k];
    float2 tk = tw[mi];
    acc = fmaf(v.x, tk.x, acc);
    acc = fmaf(-v.y, tk.y, acc);
    mi = (mi + t) & 255;
  }
  float y = (acc0 + 2.0f*acc) * (1.0f/256.0f);
  float win = 0.5f - 0.5f*cz;
  outfr[t] = y*win;
}

// ---------------- final: harmonic synth + OLA gather ----------------
__global__ __launch_bounds__(256) void k_out(const float* __restrict__ f0,
    const float* __restrict__ ws, float* __restrict__ out){
  __shared__ float win2[256];
  __shared__ float c1s[BB*32];
  {
    int t = threadIdx.x;
    double a = (2.0*M_PI/256.0)*(double)t;
    float w = (float)(0.5 - 0.5*cos(a));
    win2[t] = w*w;
    if (t < BB*32) c1s[t] = ws[OFF_C1 + t];
  }
  __syncthreads();
  int idx = blockIdx.x*256 + threadIdx.x;
  if (idx >= BB*2*NSAMP) return;
  int m = idx % NSAMP;
  int bc = idx / NSAMP;
  int ch = bc & 1, b = bc >> 1;
  // f32 interp chain (bit-exact to numpy f32 elementwise)
  int i0,i1; float w,w1;
  up_coords(m,&i0,&i1,&w,&w1);
  const float* f0b = f0 + b*TT;
  float f0u = __fadd_rn(__fmul_rn(f0b[i0], w1), __fmul_rn(f0b[i1], w));
  const float* am = ws + OFF_AMP + b*TT;
  float oa = __fadd_rn(__fmul_rn(am[i0], w1), __fmul_rn(am[i1], w));
  const float* ha = ws + (ch ? OFF_HARMR : OFF_HARML) + (size_t)b*TT*NHARM;
  float tm = (float)m;
  float hsum = 0.0f;
  for (int k=1;k<=NHARM;k++){
    float instf = __fmul_rn(f0u, (float)k);          // RN32(f0_up*k), exact mask
    if (instf < 21600.0f){
      float a0 = ha[i0*NHARM + (k-1)], a1 = ha[i1*NHARM + (k-1)];
      float ak = __fadd_rn(__fmul_rn(a0, w1), __fmul_rn(a1, w));
      float ph = __fmul_rn(c1s[b*32 + (k-1)], tm);   // RN32(c1*t): exact f32 phase
      double rev = (double)ph * 0.15915494309189535; // /(2pi) in f64
      double fr2 = rev - floor(rev);
      float rad = (float)((fr2 - (fr2 >= 0.5 ? 1.0 : 0.0)) * 6.283185307179586);
      float s = sinf(rad);                            // sin(exact f32 phase)
      hsum = __fadd_rn(hsum, __fmul_rn(ak, s));
    }
  }
  float harm = __fmul_rn(hsum, oa);
  // noise OLA gather
  int p = m + 128;
  int fhi = min(p >> 6, NFRAMES-1);
  int flo = max((p - 192) >> 6, 0);
  const float* frb = ws + (ch ? OFF_FRR : OFF_FRL) + (size_t)b*NFRAMES*256;
  float nacc = 0.0f, wsum = 0.0f;
  for (int f=flo; f<=fhi; f++){
    int n = p - f*NHOPF;
    nacc += frb[f*256 + n];
    wsum += win2[n];
  }
  float noise = nacc / fmaxf(wsum, 1e-11f);
  out[idx] = __fadd_rn(harm, noise);
}

extern "C" void kernel_launch(void* const* d_in, const int* in_sizes, int n_in,
                              void* d_out, int out_size, void* d_ws, size_t ws_size,
                              hipStream_t stream){
  const float* f0  = (const float*)d_in[0];
  const float* ldb = (const float*)d_in[1];
  const float* vel = (const float*)d_in[2];
  const float* nL  = (const float*)d_in[3];
  const float* nR  = (const float*)d_in[4];
  const float* Wp1 = (const float*)d_in[5];
  const float* bp1 = (const float*)d_in[6];
  const float* Wp2 = (const float*)d_in[7];
  const float* bp2 = (const float*)d_in[8];
  const float* Wih = (const float*)d_in[9];
  const float* Whh = (const float*)d_in[10];
  const float* bih = (const float*)d_in[11];
  const float* bhh = (const float*)d_in[12];
  const float* Wpo = (const float*)d_in[13];
  const float* bpo = (const float*)d_in[14];
  const float* WhL = (const float*)d_in[15];
  const float* bhL = (const float*)d_in[16];
  const float* WhR = (const float*)d_in[17];
  const float* bhR = (const float*)d_in[18];
  const float* Wam = (const float*)d_in[19];
  const float* bam = (const float*)d_in[20];
  const float* WnL = (const float*)d_in[21];
  const float* bnL = (const float*)d_in[22];
  const float* WnR = (const float*)d_in[23];
  const float* bnR = (const float*)d_in[24];
  float* ws = (float*)d_ws;
  float* out = (float*)d_out;

  k_enc<<<(BB*TT+255)/256, 256, 0, stream>>>(f0, ldb, vel, ws+OFF_FEAT);
  k_mm<1><<<(BB*TT*128+255)/256, 256, 0, stream>>>(ws+OFF_FEAT, Wp1, bp1, ws+OFF_H1, BB*TT, 128, FEATD);
  k_mm<1><<<(BB*TT*128+255)/256, 256, 0, stream>>>(ws+OFF_H1, Wp2, bp2, ws+OFF_H2, BB*TT, 128, 128);
  k_mm<0><<<(BB*TT*192+255)/256, 256, 0, stream>>>(ws+OFF_H2, Wih, bih, ws+OFF_GI, BB*TT, 192, 128);
  k_gru<<<BB, 64, 0, stream>>>(ws+OFF_GI, Whh, bhh, ws+OFF_GOUT);
  k_mm<1><<<(BB*TT*128+255)/256, 256, 0, stream>>>(ws+OFF_GOUT, Wpo, bpo, ws+OFF_POST, BB*TT, 128, HID);
  k_heads<<<(BB*TT*323+255)/256, 256, 0, stream>>>(ws+OFF_POST, WhL,bhL, WhR,bhR, Wam,bam, WnL,bnL, WnR,bnR,
      ws+OFF_HARML, ws+OFF_HARMR, ws+OFF_AMP, ws+OFF_NMAGL, ws+OFF_NMAGR);
  dim3 gmf(BB, 32);
  k_meanf0_np<<<gmf, 256, 0, stream>>>(f0, ws);
  dim3 gs(BB*NFRAMES, 2);
  k_stft<<<gs, 64, 0, stream>>>(nL, nR, ws);
  k_istft<<<gs, 256, 0, stream>>>(ws);
  k_out<<<(BB*2*NSAMP+255)/256, 256, 0, stream>>>(f0, ws, out);
}

// Round 6
// 694.637 us; speedup vs baseline: 8.0992x; 1.0011x over previous
//
#include <hip/hip_runtime.h>
#include <math.h>

#ifndef M_PI
#define M_PI 3.14159265358979323846
#endif

#define BB 4
#define TT 500
#define NSAMP 120000
#define NHARM 32
#define NFFT 256
#define NBIN 129
#define NHOPF 64
#define NFRAMES 1876
#define HID 64
#define MLPD 128
#define FEATD 88

#define R_MAG ((float)(500.0/1876.0))
#define R_UP_F ((float)(500.0/120000.0))

// ---- workspace layout (float offsets) ----
#define OFF_HARML 0
#define OFF_HARMR 64000
#define OFF_AMP   128000
#define OFF_NMAGL 130000
#define OFF_NMAGR 388000
#define OFF_C1    646000            /* 128 floats: RN32(c32*mf32) per (b,k) */
#define OFF_TRUNK 646128
#define OFF_FEAT  (OFF_TRUNK)
#define OFF_H1    (OFF_FEAT+176000)
#define OFF_H2    (OFF_H1+256000)
#define OFF_GI    (OFF_H2+256000)
#define OFF_GOUT  (OFF_GI+384000)
#define OFF_POST  (OFF_GOUT+128000)
/* spec reuses trunk region (trunk dead after k_heads) */
#define OFF_SPECL (OFF_TRUNK)
#define OFF_SPECR (OFF_SPECL+1936032)
#define OFF_FRL   (OFF_SPECR+1936032)
#define OFF_FRR   (OFF_FRL+1921024)
/* total = 8360240 floats = 33.44 MB */

// f32 upsample position/interp chain, bit-exact to numpy float32 elementwise
__device__ __forceinline__ void up_coords(int m, int* i0, int* i1, float* w, float* w1){
  float pos = __fadd_rn(__fmul_rn(__fadd_rn((float)m, 0.5f), R_UP_F), -0.5f);
  pos = fminf(fmaxf(pos, 0.0f), 499.0f);
  int a = (int)pos;
  *i0 = a; *i1 = min(a+1, TT-1);
  float ww = __fsub_rn(pos, (float)a);
  *w = ww; *w1 = __fsub_rn(1.0f, ww);
}
__device__ __forceinline__ float f0_up_elem(const float* __restrict__ f0s, int m){
  int i0,i1; float w,w1;
  up_coords(m,&i0,&i1,&w,&w1);
  return __fadd_rn(__fmul_rn(f0s[i0], w1), __fmul_rn(f0s[i1], w));
}

// ---------------- encoding ----------------
__global__ void k_enc(const float* __restrict__ f0, const float* __restrict__ ldb,
                      const float* __restrict__ vel, float* __restrict__ feat){
  int idx = blockIdx.x*blockDim.x + threadIdx.x;
  if (idx >= BB*TT) return;
  int b = idx / TT;
  float f = f0[idx];
  float gate = (f > 0.0f) ? 1.0f : 0.0f;
  float fs = fmaxf(f, 20.0f);
  float fn = (logf(fs) - (float)2.995732273553991) / (float)5.5214609178622464;
  fn = fminf(fmaxf(fn, 0.0f), 1.0f);
  float ln = fminf(fmaxf((ldb[idx] + 80.0f) / 80.0f, 0.0f), 1.0f);
  float vn = fminf(fmaxf(vel[b] / 7.0f, 0.0f), 1.0f);
  float* o = feat + idx*FEATD;
  #pragma unroll 4
  for (int i=1;i<=32;i++){
    float ang = (float)M_PI * (float)i * fn;
    o[2*i-2] = sinf(ang)*gate;
    o[2*i-1] = cosf(ang)*gate;
  }
  #pragma unroll
  for (int i=1;i<=8;i++){
    float ang = (float)M_PI * (float)i * ln;
    o[64+2*i-2] = sinf(ang);
    o[64+2*i-1] = cosf(ang);
  }
  #pragma unroll
  for (int i=1;i<=4;i++){
    float ang = (float)M_PI * (float)i * vn;
    o[80+2*i-2] = sinf(ang);
    o[80+2*i-1] = cosf(ang);
  }
}

// ---------------- generic matmul: out = act(in @ W^T + b) ----------------
template<int ACT>
__global__ void k_mm(const float* __restrict__ in, const float* __restrict__ W,
                     const float* __restrict__ bias, float* __restrict__ out,
                     int R, int C, int IN){
  int idx = blockIdx.x*blockDim.x + threadIdx.x;
  if (idx >= R*C) return;
  int r = idx / C, c = idx - r*C;
  const float* ip = in + r*IN;
  const float* wp = W + c*IN;
  float acc = bias[c];
  #pragma unroll 8
  for (int i=0;i<IN;i++) acc = fmaf(ip[i], wp[i], acc);
  if (ACT==1) acc = fmaxf(acc, 0.0f);
  out[idx] = acc;
}

// ---------------- GRU recurrence (gi precomputed) ----------------
// Single wave per batch. h broadcast via v_readlane (wave-uniform -> SGPR).
// Weights pinned in VGPRs via empty asm (blocks the compiler's
// remat-from-memory, which was re-loading 192 floats/lane/iter from L2:
// round-5 profile showed VGPR_Count=108 < 192 needed, 1600 cyc/iter).
__global__ __launch_bounds__(64,1) void k_gru(const float* __restrict__ gi,
    const float* __restrict__ Whh, const float* __restrict__ bhh,
    float* __restrict__ gout){
  int b = blockIdx.x;
  int j = threadIdx.x;
  float wr[64], wz[64], wn[64];
  #pragma unroll
  for (int i=0;i<16;i++){
    float4 a = *(const float4*)(Whh + (j)*64     + i*4);
    float4 c = *(const float4*)(Whh + (64+j)*64  + i*4);
    float4 d = *(const float4*)(Whh + (128+j)*64 + i*4);
    wr[4*i]=a.x; wr[4*i+1]=a.y; wr[4*i+2]=a.z; wr[4*i+3]=a.w;
    wz[4*i]=c.x; wz[4*i+1]=c.y; wz[4*i+2]=c.z; wz[4*i+3]=c.w;
    wn[4*i]=d.x; wn[4*i+1]=d.y; wn[4*i+2]=d.z; wn[4*i+3]=d.w;
  }
  // Pin all 192 weight values into VGPRs: the asm "may modify" them, so the
  // compiler cannot re-load from global inside the loop; values stay live.
  #pragma unroll
  for (int i=0;i<64;i++){
    asm volatile("" : "+v"(wr[i]), "+v"(wz[i]), "+v"(wn[i]));
  }
  float br = bhh[j], bz = bhh[64+j], bn = bhh[128+j];
  const float* gp = gi + (size_t)b*TT*192 + j;
  float* op = gout + (size_t)b*TT*64 + j;
  float hreg = 0.0f;
  float gr = gp[0], gz = gp[64], gn = gp[128];
  for (int t=0;t<TT;t++){
    // prefetch next step's gate inputs (independent of recurrence)
    int tn = min(t+1, TT-1);
    float gr2 = gp[tn*192], gz2 = gp[tn*192+64], gn2 = gp[tn*192+128];
    float ar=0.f, az=0.f, an=0.f;
    #pragma unroll
    for (int i=0;i<64;i++){
      float hi = __uint_as_float(__builtin_amdgcn_readlane(__float_as_uint(hreg), i));
      ar = fmaf(wr[i], hi, ar);
      az = fmaf(wz[i], hi, az);
      an = fmaf(wn[i], hi, an);
    }
    float r = 1.0f/(1.0f+expf(-(gr+ar+br)));
    float z = 1.0f/(1.0f+expf(-(gz+az+bz)));
    float n = tanhf(gn + r*(an+bn));
    hreg = (1.0f - z)*n + z*hreg;
    op[t*64] = hreg;
    gr=gr2; gz=gz2; gn=gn2;
  }
}

// ---------------- heads ----------------
__global__ void k_heads(const float* __restrict__ post,
  const float* __restrict__ WhL, const float* __restrict__ bhL,
  const float* __restrict__ WhR, const float* __restrict__ bhR,
  const float* __restrict__ Wam, const float* __restrict__ bam,
  const float* __restrict__ WnL, const float* __restrict__ bnL,
  const float* __restrict__ WnR, const float* __restrict__ bnR,
  float* __restrict__ harmL, float* __restrict__ harmR, float* __restrict__ amp,
  float* __restrict__ nmagL, float* __restrict__ nmagR){
  int idx = blockIdx.x*blockDim.x + threadIdx.x;
  if (idx >= BB*TT*323) return;
  int r = idx / 323, c = idx - r*323;
  const float* W; const float* bb; float* o; int oc, ow; bool sp=false;
  if (c < 32)      { W=WhL; bb=bhL; o=harmL; oc=c;     ow=32; }
  else if (c < 64) { W=WhR; bb=bhR; o=harmR; oc=c-32;  ow=32; }
  else if (c == 64){ W=Wam; bb=bam; o=amp;   oc=0;     ow=1; sp=true; }
  else if (c < 194){ W=WnL; bb=bnL; o=nmagL; oc=c-65;  ow=129; }
  else             { W=WnR; bb=bnR; o=nmagR; oc=c-194; ow=129; }
  const float* ip = post + r*MLPD;
  const float* wp = W + oc*MLPD;
  float acc = bb[oc];
  #pragma unroll 8
  for (int i=0;i<MLPD;i++) acc = fmaf(ip[i], wp[i], acc);
  float v;
  if (sp) v = fmaxf(acc, 0.0f) + log1pf(expf(-fabsf(acc)));   // softplus (stable)
  else    v = 1.0f/(1.0f+expf(-acc));                          // sigmoid
  o[r*ow + oc] = v;
}

// ---------------- numpy-exact pairwise mean of inst_freq per (b,k) ----------------
// numpy pairwise_sum_FLOAT on n=120000 forms a PERFECT depth-10 binary tree:
// 1024 leaves (n<=128) all at depth 10; combine == pairwise-adjacent tree.
__device__ float np_block_sum(const float* __restrict__ f0s, int off, int n, float kf){
  float r[8];
  #pragma unroll
  for (int j=0;j<8;j++) r[j] = __fmul_rn(f0_up_elem(f0s, off+j), kf);
  int lim = n - (n & 7);
  int i = 8;
  for (; i<lim; i+=8){
    #pragma unroll
    for (int j=0;j<8;j++)
      r[j] = __fadd_rn(r[j], __fmul_rn(f0_up_elem(f0s, off+i+j), kf));
  }
  float res = __fadd_rn(__fadd_rn(__fadd_rn(r[0],r[1]), __fadd_rn(r[2],r[3])),
                        __fadd_rn(__fadd_rn(r[4],r[5]), __fadd_rn(r[6],r[7])));
  for (; i<n; i++)
    res = __fadd_rn(res, __fmul_rn(f0_up_elem(f0s, off+i), kf));
  return res;
}

__global__ __launch_bounds__(256) void k_meanf0_np(const float* __restrict__ f0, float* __restrict__ ws){
  int b = blockIdx.x;
  int k = blockIdx.y;           // 0..31 -> harmonic k+1
  float kf = (float)(k+1);
  int tid = threadIdx.x;
  __shared__ float f0s[TT];
  __shared__ float red[256];
  for (int i=tid;i<TT;i+=256) f0s[i] = f0[b*TT+i];
  __syncthreads();
  // 4 adjacent leaves per thread; combine = depth-8 subtree ((l0+l1)+(l2+l3))
  float lv[4];
  #pragma unroll
  for (int q=0;q<4;q++){
    int leafIdx = tid*4 + q;
    int off = 0, n = NSAMP;
    #pragma unroll
    for (int lvl=9; lvl>=0; --lvl){
      int n2 = (n>>1); n2 -= (n2 & 7);
      if ((leafIdx >> lvl) & 1){ off += n2; n -= n2; } else { n = n2; }
    }
    lv[q] = np_block_sum(f0s, off, n, kf);
  }
  red[tid] = __fadd_rn(__fadd_rn(lv[0],lv[1]), __fadd_rn(lv[2],lv[3]));
  __syncthreads();
  // 8-level pairwise-adjacent LDS reduction (exact recursion order)
  for (int cnt=256; cnt>1; cnt>>=1){
    float v = 0.0f;
    int half = cnt>>1;
    if (tid < half) v = __fadd_rn(red[2*tid], red[2*tid+1]);
    __syncthreads();
    if (tid < half) red[tid] = v;
    __syncthreads();
  }
  if (tid==0){
    float mf = __fdiv_rn(red[0], 120000.0f);                  // np.mean: sum/n in f32
    float c1 = __fmul_rn((float)(2.0*M_PI/48000.0), mf);      // RN32(c32*mf32)
    ws[OFF_C1 + b*32 + k] = c1;
  }
}

// ---------------- forward STFT (windowed frames -> rfft bins) ----------------
__global__ __launch_bounds__(64) void k_stft(const float* __restrict__ nL, const float* __restrict__ nR,
                                             float* __restrict__ ws){
  int fr = blockIdx.x;           // b*NFRAMES + f
  int ch = blockIdx.y;
  int b = fr / NFRAMES, f = fr - b*NFRAMES;
  const float* x = (ch ? nR : nL) + (size_t)b*NSAMP;
  float* spec = ws + (ch ? OFF_SPECR : OFF_SPECL) + (size_t)fr*258;
  int j = threadIdx.x;
  __shared__ float frs[256];
  __shared__ float2 tw[256];
  for (int n=j;n<256;n+=64){
    double a = (2.0*M_PI/256.0)*(double)n;
    tw[n] = make_float2((float)cos(a), (float)sin(a));
    int xi = f*NHOPF + n - 128;
    xi = xi < 0 ? -xi : xi;
    xi = xi >= NSAMP ? 2*(NSAMP-1)-xi : xi;
    float w = (float)(0.5 - 0.5*cos(a));
    frs[n] = x[xi]*w;
  }
  __syncthreads();
  float re0=0.f, im0=0.f, re1=0.f, im1=0.f;
  int m0 = 0;                       // (j*n) & 255, incrementally
  #pragma unroll 4
  for (int n=0;n<256;n++){
    float fv = frs[n];
    int m1 = (m0 + ((n&3)<<6)) & 255;
    float2 t0 = tw[m0], t1 = tw[m1];
    re0 = fmaf(fv, t0.x, re0); im0 = fmaf(-fv, t0.y, im0);
    re1 = fmaf(fv, t1.x, re1); im1 = fmaf(-fv, t1.y, im1);
    m0 = (m0 + j) & 255;
  }
  // Nyquist bin 128: sum of (-1)^n * frs[n]; n = j + 64q -> sign = (-1)^j
  float p = frs[j] + frs[j+64] + frs[j+128] + frs[j+192];
  p = (j & 1) ? -p : p;
  for (int o=32;o>0;o>>=1) p += __shfl_down(p, o, 64);
  spec[2*j]   = re0; spec[2*j+1]   = im0;
  spec[2*(j+64)] = re1; spec[2*(j+64)+1] = im1;
  if (j==0){ spec[256] = p; spec[257] = 0.0f; }
}

// ---------------- mag filter + irfft + window ----------------
__global__ __launch_bounds__(256) void k_istft(float* __restrict__ ws){
  int fr = blockIdx.x;
  int ch = blockIdx.y;
  int b = fr / NFRAMES, f = fr - b*NFRAMES;
  const float* spec = ws + (ch ? OFF_SPECR : OFF_SPECL) + (size_t)fr*258;
  const float* nmag = ws + (ch ? OFF_NMAGR : OFF_NMAGL) + (size_t)b*TT*NBIN;
  float* outfr = ws + (ch ? OFF_FRR : OFF_FRL) + (size_t)fr*256;
  int t = threadIdx.x;
  __shared__ float2 tw[256];
  __shared__ float2 mx[NBIN];
  double a = (2.0*M_PI/256.0)*(double)t;
  float cz = (float)cos(a), sz = (float)sin(a);
  tw[t] = make_float2(cz, sz);
  if (t < NBIN){
    float pos = ((float)f + 0.5f) * R_MAG - 0.5f;
    pos = fminf(fmaxf(pos, 0.0f), 499.0f);
    int i0 = (int)pos, i1 = min(i0+1, TT-1);
    float w = pos - (float)i0;
    float mg = nmag[i0*NBIN + t]*(1.0f-w) + nmag[i1*NBIN + t]*w;
    mx[t] = make_float2(spec[2*t]*mg, spec[2*t+1]*mg);
  }
  __syncthreads();
  float acc0 = mx[0].x + ((t&1) ? -mx[128].x : mx[128].x);
  float acc = 0.0f;
  int mi = t;                      // (k*t)&255 for k=1
  #pragma unroll 4
  for (int k=1;k<128;k++){
    float2 v = mx[k];
    float2 tk = tw[mi];
    acc = fmaf(v.x, tk.x, acc);
    acc = fmaf(-v.y, tk.y, acc);
    mi = (mi + t) & 255;
  }
  float y = (acc0 + 2.0f*acc) * (1.0f/256.0f);
  float win = 0.5f - 0.5f*cz;
  outfr[t] = y*win;
}

// ---------------- final: harmonic synth + OLA gather ----------------
__global__ __launch_bounds__(256) void k_out(const float* __restrict__ f0,
    const float* __restrict__ ws, float* __restrict__ out){
  __shared__ float win2[256];
  __shared__ float c1s[BB*32];
  {
    int t = threadIdx.x;
    double a = (2.0*M_PI/256.0)*(double)t;
    float w = (float)(0.5 - 0.5*cos(a));
    win2[t] = w*w;
    if (t < BB*32) c1s[t] = ws[OFF_C1 + t];
  }
  __syncthreads();
  int idx = blockIdx.x*256 + threadIdx.x;
  if (idx >= BB*2*NSAMP) return;
  int m = idx % NSAMP;
  int bc = idx / NSAMP;
  int ch = bc & 1, b = bc >> 1;
  // f32 interp chain (bit-exact to numpy f32 elementwise)
  int i0,i1; float w,w1;
  up_coords(m,&i0,&i1,&w,&w1);
  const float* f0b = f0 + b*TT;
  float f0u = __fadd_rn(__fmul_rn(f0b[i0], w1), __fmul_rn(f0b[i1], w));
  const float* am = ws + OFF_AMP + b*TT;
  float oa = __fadd_rn(__fmul_rn(am[i0], w1), __fmul_rn(am[i1], w));
  const float* ha = ws + (ch ? OFF_HARMR : OFF_HARML) + (size_t)b*TT*NHARM;
  float tm = (float)m;
  float hsum = 0.0f;
  for (int k=1;k<=NHARM;k++){
    float instf = __fmul_rn(f0u, (float)k);          // RN32(f0_up*k), exact mask
    if (instf < 21600.0f){
      float a0 = ha[i0*NHARM + (k-1)], a1 = ha[i1*NHARM + (k-1)];
      float ak = __fadd_rn(__fmul_rn(a0, w1), __fmul_rn(a1, w));
      float ph = __fmul_rn(c1s[b*32 + (k-1)], tm);   // RN32(c1*t): exact f32 phase
      double rev = (double)ph * 0.15915494309189535; // /(2pi) in f64
      double fr2 = rev - floor(rev);
      float rad = (float)((fr2 - (fr2 >= 0.5 ? 1.0 : 0.0)) * 6.283185307179586);
      float s = sinf(rad);                            // sin(exact f32 phase)
      hsum = __fadd_rn(hsum, __fmul_rn(ak, s));
    }
  }
  float harm = __fmul_rn(hsum, oa);
  // noise OLA gather
  int p = m + 128;
  int fhi = min(p >> 6, NFRAMES-1);
  int flo = max((p - 192) >> 6, 0);
  const float* frb = ws + (ch ? OFF_FRR : OFF_FRL) + (size_t)b*NFRAMES*256;
  float nacc = 0.0f, wsum = 0.0f;
  for (int f=flo; f<=fhi; f++){
    int n = p - f*NHOPF;
    nacc += frb[f*256 + n];
    wsum += win2[n];
  }
  float noise = nacc / fmaxf(wsum, 1e-11f);
  out[idx] = __fadd_rn(harm, noise);
}

extern "C" void kernel_launch(void* const* d_in, const int* in_sizes, int n_in,
                              void* d_out, int out_size, void* d_ws, size_t ws_size,
                              hipStream_t stream){
  const float* f0  = (const float*)d_in[0];
  const float* ldb = (const float*)d_in[1];
  const float* vel = (const float*)d_in[2];
  const float* nL  = (const float*)d_in[3];
  const float* nR  = (const float*)d_in[4];
  const float* Wp1 = (const float*)d_in[5];
  const float* bp1 = (const float*)d_in[6];
  const float* Wp2 = (const float*)d_in[7];
  const float* bp2 = (const float*)d_in[8];
  const float* Wih = (const float*)d_in[9];
  const float* Whh = (const float*)d_in[10];
  const float* bih = (const float*)d_in[11];
  const float* bhh = (const float*)d_in[12];
  const float* Wpo = (const float*)d_in[13];
  const float* bpo = (const float*)d_in[14];
  const float* WhL = (const float*)d_in[15];
  const float* bhL = (const float*)d_in[16];
  const float* WhR = (const float*)d_in[17];
  const float* bhR = (const float*)d_in[18];
  const float* Wam = (const float*)d_in[19];
  const float* bam = (const float*)d_in[20];
  const float* WnL = (const float*)d_in[21];
  const float* bnL = (const float*)d_in[22];
  const float* WnR = (const float*)d_in[23];
  const float* bnR = (const float*)d_in[24];
  float* ws = (float*)d_ws;
  float* out = (float*)d_out;

  k_enc<<<(BB*TT+255)/256, 256, 0, stream>>>(f0, ldb, vel, ws+OFF_FEAT);
  k_mm<1><<<(BB*TT*128+255)/256, 256, 0, stream>>>(ws+OFF_FEAT, Wp1, bp1, ws+OFF_H1, BB*TT, 128, FEATD);
  k_mm<1><<<(BB*TT*128+255)/256, 256, 0, stream>>>(ws+OFF_H1, Wp2, bp2, ws+OFF_H2, BB*TT, 128, 128);
  k_mm<0><<<(BB*TT*192+255)/256, 256, 0, stream>>>(ws+OFF_H2, Wih, bih, ws+OFF_GI, BB*TT, 192, 128);
  k_gru<<<BB, 64, 0, stream>>>(ws+OFF_GI, Whh, bhh, ws+OFF_GOUT);
  k_mm<1><<<(BB*TT*128+255)/256, 256, 0, stream>>>(ws+OFF_GOUT, Wpo, bpo, ws+OFF_POST, BB*TT, 128, HID);
  k_heads<<<(BB*TT*323+255)/256, 256, 0, stream>>>(ws+OFF_POST, WhL,bhL, WhR,bhR, Wam,bam, WnL,bnL, WnR,bnR,
      ws+OFF_HARML, ws+OFF_HARMR, ws+OFF_AMP, ws+OFF_NMAGL, ws+OFF_NMAGR);
  dim3 gmf(BB, 32);
  k_meanf0_np<<<gmf, 256, 0, stream>>>(f0, ws);
  dim3 gs(BB*NFRAMES, 2);
  k_stft<<<gs, 64, 0, stream>>>(nL, nR, ws);
  k_istft<<<gs, 256, 0, stream>>>(ws);
  k_out<<<(BB*2*NSAMP+255)/256, 256, 0, stream>>>(f0, ws, out);
}

// Round 7
// 668.293 us; speedup vs baseline: 8.4185x; 1.0394x over previous
//
#include <hip/hip_runtime.h>
#include <math.h>

#ifndef M_PI
#define M_PI 3.14159265358979323846
#endif

#define BB 4
#define TT 500
#define NSAMP 120000
#define NHARM 32
#define NFFT 256
#define NBIN 129
#define NHOPF 64
#define NFRAMES 1876
#define HID 64
#define MLPD 128
#define FEATD 88

#define R_MAG ((float)(500.0/1876.0))
#define R_UP_F ((float)(500.0/120000.0))

// ---- workspace layout (float offsets) ----
#define OFF_HARML 0
#define OFF_HARMR 64000
#define OFF_AMP   128000
#define OFF_NMAGL 130000
#define OFF_NMAGR 388000
#define OFF_C1    646000            /* 128 floats: RN32(c32*mf32) per (b,k) */
#define OFF_TRUNK 646128
#define OFF_FEAT  (OFF_TRUNK)
#define OFF_H1    (OFF_FEAT+176000)
#define OFF_H2    (OFF_H1+256000)
#define OFF_GI    (OFF_H2+256000)
#define OFF_GOUT  (OFF_GI+384000)
#define OFF_POST  (OFF_GOUT+128000)
/* spec reuses trunk region (trunk dead after k_heads) */
#define OFF_SPECL (OFF_TRUNK)
#define OFF_SPECR (OFF_SPECL+1936032)
#define OFF_FRL   (OFF_SPECR+1936032)
#define OFF_FRR   (OFF_FRL+1921024)
/* total = 8360240 floats = 33.44 MB */

// f32 upsample position/interp chain, bit-exact to numpy float32 elementwise
__device__ __forceinline__ void up_coords(int m, int* i0, int* i1, float* w, float* w1){
  float pos = __fadd_rn(__fmul_rn(__fadd_rn((float)m, 0.5f), R_UP_F), -0.5f);
  pos = fminf(fmaxf(pos, 0.0f), 499.0f);
  int a = (int)pos;
  *i0 = a; *i1 = min(a+1, TT-1);
  float ww = __fsub_rn(pos, (float)a);
  *w = ww; *w1 = __fsub_rn(1.0f, ww);
}
__device__ __forceinline__ float f0_up_elem(const float* __restrict__ f0s, int m){
  int i0,i1; float w,w1;
  up_coords(m,&i0,&i1,&w,&w1);
  return __fadd_rn(__fmul_rn(f0s[i0], w1), __fmul_rn(f0s[i1], w));
}

// ---------------- encoding ----------------
__global__ void k_enc(const float* __restrict__ f0, const float* __restrict__ ldb,
                      const float* __restrict__ vel, float* __restrict__ feat){
  int idx = blockIdx.x*blockDim.x + threadIdx.x;
  if (idx >= BB*TT) return;
  int b = idx / TT;
  float f = f0[idx];
  float gate = (f > 0.0f) ? 1.0f : 0.0f;
  float fs = fmaxf(f, 20.0f);
  float fn = (logf(fs) - (float)2.995732273553991) / (float)5.5214609178622464;
  fn = fminf(fmaxf(fn, 0.0f), 1.0f);
  float ln = fminf(fmaxf((ldb[idx] + 80.0f) / 80.0f, 0.0f), 1.0f);
  float vn = fminf(fmaxf(vel[b] / 7.0f, 0.0f), 1.0f);
  float* o = feat + idx*FEATD;
  #pragma unroll 4
  for (int i=1;i<=32;i++){
    float ang = (float)M_PI * (float)i * fn;
    o[2*i-2] = sinf(ang)*gate;
    o[2*i-1] = cosf(ang)*gate;
  }
  #pragma unroll
  for (int i=1;i<=8;i++){
    float ang = (float)M_PI * (float)i * ln;
    o[64+2*i-2] = sinf(ang);
    o[64+2*i-1] = cosf(ang);
  }
  #pragma unroll
  for (int i=1;i<=4;i++){
    float ang = (float)M_PI * (float)i * vn;
    o[80+2*i-2] = sinf(ang);
    o[80+2*i-1] = cosf(ang);
  }
}

// ---------------- generic matmul: out = act(in @ W^T + b) ----------------
template<int ACT>
__global__ void k_mm(const float* __restrict__ in, const float* __restrict__ W,
                     const float* __restrict__ bias, float* __restrict__ out,
                     int R, int C, int IN){
  int idx = blockIdx.x*blockDim.x + threadIdx.x;
  if (idx >= R*C) return;
  int r = idx / C, c = idx - r*C;
  const float* ip = in + r*IN;
  const float* wp = W + c*IN;
  float acc = bias[c];
  #pragma unroll 8
  for (int i=0;i<IN;i++) acc = fmaf(ip[i], wp[i], acc);
  if (ACT==1) acc = fmaxf(acc, 0.0f);
  out[idx] = acc;
}

// ---------------- GRU recurrence (gi precomputed) ----------------
// 3 waves/block: wave g owns gate g (r,z,n); lane j owns output (g,j) and
// holds ONLY its 64 weights (~80 VGPR total -> no spill at ANY allocator
// budget; rounds 5/6 showed a 108-VGPR budget forcing 192 weights/lane to
// scratch, ~1000 cyc/iter of L2 reloads). h exchanged via 1KB LDS.
// Dot product keeps the exact sequential i=0..63 single-accumulator fmaf
// chain of the passing version -> bit-identical trajectory.
__global__ __launch_bounds__(192,1) void k_gru(const float* __restrict__ gi,
    const float* __restrict__ Whh, const float* __restrict__ bhh,
    float* __restrict__ gout){
  int b = blockIdx.x;
  int tid = threadIdx.x;        // 0..191
  int g = tid >> 6;             // gate index = wave index
  int j = tid & 63;
  float w[64];
  #pragma unroll
  for (int i=0;i<16;i++){
    float4 v = *(const float4*)(Whh + (size_t)(g*64+j)*64 + i*4);
    w[4*i]=v.x; w[4*i+1]=v.y; w[4*i+2]=v.z; w[4*i+3]=v.w;
  }
  __shared__ __align__(16) float hsh[64];
  __shared__ float ash[192];
  float br=0.f, bz=0.f, bn=0.f, hreg=0.f;
  const float* gp = gi + (size_t)b*TT*192 + j;
  float* op = gout + (size_t)b*TT*64 + j;
  float gr=0.f, gz=0.f, gn=0.f;
  if (g==0){
    br = bhh[j]; bz = bhh[64+j]; bn = bhh[128+j];
    gr = gp[0]; gz = gp[64]; gn = gp[128];
    hsh[j] = 0.0f;
  }
  __syncthreads();
  for (int t=0;t<TT;t++){
    // prefetch next step's gate inputs early (latency hides under the dot)
    float gr2=0.f, gz2=0.f, gn2=0.f;
    if (g==0){
      int tn = min(t+1, TT-1);
      gr2 = gp[tn*192]; gz2 = gp[tn*192+64]; gn2 = gp[tn*192+128];
    }
    // dot(w, h): exact sequential chain i=0..63 (bit-identical to before)
    float acc = 0.f;
    #pragma unroll
    for (int i=0;i<16;i++){
      float4 h4 = *(const float4*)(hsh + 4*i);   // broadcast read
      acc = fmaf(w[4*i],   h4.x, acc);
      acc = fmaf(w[4*i+1], h4.y, acc);
      acc = fmaf(w[4*i+2], h4.z, acc);
      acc = fmaf(w[4*i+3], h4.w, acc);
    }
    ash[tid] = acc;
    __syncthreads();
    if (g==0){
      float ar = acc, az = ash[64+j], an = ash[128+j];
      float r = 1.0f/(1.0f+expf(-(gr+ar+br)));
      float z = 1.0f/(1.0f+expf(-(gz+az+bz)));
      float n = tanhf(gn + r*(an+bn));
      hreg = (1.0f - z)*n + z*hreg;
      op[t*64] = hreg;
      hsh[j] = hreg;
      gr=gr2; gz=gz2; gn=gn2;
    }
    __syncthreads();
  }
}

// ---------------- heads ----------------
__global__ void k_heads(const float* __restrict__ post,
  const float* __restrict__ WhL, const float* __restrict__ bhL,
  const float* __restrict__ WhR, const float* __restrict__ bhR,
  const float* __restrict__ Wam, const float* __restrict__ bam,
  const float* __restrict__ WnL, const float* __restrict__ bnL,
  const float* __restrict__ WnR, const float* __restrict__ bnR,
  float* __restrict__ harmL, float* __restrict__ harmR, float* __restrict__ amp,
  float* __restrict__ nmagL, float* __restrict__ nmagR){
  int idx = blockIdx.x*blockDim.x + threadIdx.x;
  if (idx >= BB*TT*323) return;
  int r = idx / 323, c = idx - r*323;
  const float* W; const float* bb; float* o; int oc, ow; bool sp=false;
  if (c < 32)      { W=WhL; bb=bhL; o=harmL; oc=c;     ow=32; }
  else if (c < 64) { W=WhR; bb=bhR; o=harmR; oc=c-32;  ow=32; }
  else if (c == 64){ W=Wam; bb=bam; o=amp;   oc=0;     ow=1; sp=true; }
  else if (c < 194){ W=WnL; bb=bnL; o=nmagL; oc=c-65;  ow=129; }
  else             { W=WnR; bb=bnR; o=nmagR; oc=c-194; ow=129; }
  const float* ip = post + r*MLPD;
  const float* wp = W + oc*MLPD;
  float acc = bb[oc];
  #pragma unroll 8
  for (int i=0;i<MLPD;i++) acc = fmaf(ip[i], wp[i], acc);
  float v;
  if (sp) v = fmaxf(acc, 0.0f) + log1pf(expf(-fabsf(acc)));   // softplus (stable)
  else    v = 1.0f/(1.0f+expf(-acc));                          // sigmoid
  o[r*ow + oc] = v;
}

// ---------------- numpy-exact pairwise mean of inst_freq per (b,k) ----------------
// numpy pairwise_sum_FLOAT on n=120000 forms a PERFECT depth-10 binary tree:
// 1024 leaves (n<=128) all at depth 10; combine == pairwise-adjacent tree.
__device__ float np_block_sum(const float* __restrict__ f0s, int off, int n, float kf){
  float r[8];
  #pragma unroll
  for (int j=0;j<8;j++) r[j] = __fmul_rn(f0_up_elem(f0s, off+j), kf);
  int lim = n - (n & 7);
  int i = 8;
  for (; i<lim; i+=8){
    #pragma unroll
    for (int j=0;j<8;j++)
      r[j] = __fadd_rn(r[j], __fmul_rn(f0_up_elem(f0s, off+i+j), kf));
  }
  float res = __fadd_rn(__fadd_rn(__fadd_rn(r[0],r[1]), __fadd_rn(r[2],r[3])),
                        __fadd_rn(__fadd_rn(r[4],r[5]), __fadd_rn(r[6],r[7])));
  for (; i<n; i++)
    res = __fadd_rn(res, __fmul_rn(f0_up_elem(f0s, off+i), kf));
  return res;
}

__global__ __launch_bounds__(256) void k_meanf0_np(const float* __restrict__ f0, float* __restrict__ ws){
  int b = blockIdx.x;
  int k = blockIdx.y;           // 0..31 -> harmonic k+1
  float kf = (float)(k+1);
  int tid = threadIdx.x;
  __shared__ float f0s[TT];
  __shared__ float red[256];
  for (int i=tid;i<TT;i+=256) f0s[i] = f0[b*TT+i];
  __syncthreads();
  // 4 adjacent leaves per thread; combine = depth-8 subtree ((l0+l1)+(l2+l3))
  float lv[4];
  #pragma unroll
  for (int q=0;q<4;q++){
    int leafIdx = tid*4 + q;
    int off = 0, n = NSAMP;
    #pragma unroll
    for (int lvl=9; lvl>=0; --lvl){
      int n2 = (n>>1); n2 -= (n2 & 7);
      if ((leafIdx >> lvl) & 1){ off += n2; n -= n2; } else { n = n2; }
    }
    lv[q] = np_block_sum(f0s, off, n, kf);
  }
  red[tid] = __fadd_rn(__fadd_rn(lv[0],lv[1]), __fadd_rn(lv[2],lv[3]));
  __syncthreads();
  // 8-level pairwise-adjacent LDS reduction (exact recursion order)
  for (int cnt=256; cnt>1; cnt>>=1){
    float v = 0.0f;
    int half = cnt>>1;
    if (tid < half) v = __fadd_rn(red[2*tid], red[2*tid+1]);
    __syncthreads();
    if (tid < half) red[tid] = v;
    __syncthreads();
  }
  if (tid==0){
    float mf = __fdiv_rn(red[0], 120000.0f);                  // np.mean: sum/n in f32
    float c1 = __fmul_rn((float)(2.0*M_PI/48000.0), mf);      // RN32(c32*mf32)
    ws[OFF_C1 + b*32 + k] = c1;
  }
}

// ---------------- forward STFT (windowed frames -> rfft bins) ----------------
__global__ __launch_bounds__(64) void k_stft(const float* __restrict__ nL, const float* __restrict__ nR,
                                             float* __restrict__ ws){
  int fr = blockIdx.x;           // b*NFRAMES + f
  int ch = blockIdx.y;
  int b = fr / NFRAMES, f = fr - b*NFRAMES;
  const float* x = (ch ? nR : nL) + (size_t)b*NSAMP;
  float* spec = ws + (ch ? OFF_SPECR : OFF_SPECL) + (size_t)fr*258;
  int j = threadIdx.x;
  __shared__ float frs[256];
  __shared__ float2 tw[256];
  for (int n=j;n<256;n+=64){
    double a = (2.0*M_PI/256.0)*(double)n;
    tw[n] = make_float2((float)cos(a), (float)sin(a));
    int xi = f*NHOPF + n - 128;
    xi = xi < 0 ? -xi : xi;
    xi = xi >= NSAMP ? 2*(NSAMP-1)-xi : xi;
    float w = (float)(0.5 - 0.5*cos(a));
    frs[n] = x[xi]*w;
  }
  __syncthreads();
  float re0=0.f, im0=0.f, re1=0.f, im1=0.f;
  int m0 = 0;                       // (j*n) & 255, incrementally
  #pragma unroll 4
  for (int n=0;n<256;n++){
    float fv = frs[n];
    int m1 = (m0 + ((n&3)<<6)) & 255;
    float2 t0 = tw[m0], t1 = tw[m1];
    re0 = fmaf(fv, t0.x, re0); im0 = fmaf(-fv, t0.y, im0);
    re1 = fmaf(fv, t1.x, re1); im1 = fmaf(-fv, t1.y, im1);
    m0 = (m0 + j) & 255;
  }
  // Nyquist bin 128: sum of (-1)^n * frs[n]; n = j + 64q -> sign = (-1)^j
  float p = frs[j] + frs[j+64] + frs[j+128] + frs[j+192];
  p = (j & 1) ? -p : p;
  for (int o=32;o>0;o>>=1) p += __shfl_down(p, o, 64);
  spec[2*j]   = re0; spec[2*j+1]   = im0;
  spec[2*(j+64)] = re1; spec[2*(j+64)+1] = im1;
  if (j==0){ spec[256] = p; spec[257] = 0.0f; }
}

// ---------------- mag filter + irfft + window ----------------
__global__ __launch_bounds__(256) void k_istft(float* __restrict__ ws){
  int fr = blockIdx.x;
  int ch = blockIdx.y;
  int b = fr / NFRAMES, f = fr - b*NFRAMES;
  const float* spec = ws + (ch ? OFF_SPECR : OFF_SPECL) + (size_t)fr*258;
  const float* nmag = ws + (ch ? OFF_NMAGR : OFF_NMAGL) + (size_t)b*TT*NBIN;
  float* outfr = ws + (ch ? OFF_FRR : OFF_FRL) + (size_t)fr*256;
  int t = threadIdx.x;
  __shared__ float2 tw[256];
  __shared__ float2 mx[NBIN];
  double a = (2.0*M_PI/256.0)*(double)t;
  float cz = (float)cos(a), sz = (float)sin(a);
  tw[t] = make_float2(cz, sz);
  if (t < NBIN){
    float pos = ((float)f + 0.5f) * R_MAG - 0.5f;
    pos = fminf(fmaxf(pos, 0.0f), 499.0f);
    int i0 = (int)pos, i1 = min(i0+1, TT-1);
    float w = pos - (float)i0;
    float mg = nmag[i0*NBIN + t]*(1.0f-w) + nmag[i1*NBIN + t]*w;
    mx[t] = make_float2(spec[2*t]*mg, spec[2*t+1]*mg);
  }
  __syncthreads();
  float acc0 = mx[0].x + ((t&1) ? -mx[128].x : mx[128].x);
  float acc = 0.0f;
  int mi = t;                      // (k*t)&255 for k=1
  #pragma unroll 4
  for (int k=1;k<128;k++){
    float2 v = mx[k];
    float2 tk = tw[mi];
    acc = fmaf(v.x, tk.x, acc);
    acc = fmaf(-v.y, tk.y, acc);
    mi = (mi + t) & 255;
  }
  float y = (acc0 + 2.0f*acc) * (1.0f/256.0f);
  float win = 0.5f - 0.5f*cz;
  outfr[t] = y*win;
}

// ---------------- final: harmonic synth + OLA gather ----------------
__global__ __launch_bounds__(256) void k_out(const float* __restrict__ f0,
    const float* __restrict__ ws, float* __restrict__ out){
  __shared__ float win2[256];
  __shared__ float c1s[BB*32];
  {
    int t = threadIdx.x;
    double a = (2.0*M_PI/256.0)*(double)t;
    float w = (float)(0.5 - 0.5*cos(a));
    win2[t] = w*w;
    if (t < BB*32) c1s[t] = ws[OFF_C1 + t];
  }
  __syncthreads();
  int idx = blockIdx.x*256 + threadIdx.x;
  if (idx >= BB*2*NSAMP) return;
  int m = idx % NSAMP;
  int bc = idx / NSAMP;
  int ch = bc & 1, b = bc >> 1;
  // f32 interp chain (bit-exact to numpy f32 elementwise)
  int i0,i1; float w,w1;
  up_coords(m,&i0,&i1,&w,&w1);
  const float* f0b = f0 + b*TT;
  float f0u = __fadd_rn(__fmul_rn(f0b[i0], w1), __fmul_rn(f0b[i1], w));
  const float* am = ws + OFF_AMP + b*TT;
  float oa = __fadd_rn(__fmul_rn(am[i0], w1), __fmul_rn(am[i1], w));
  const float* ha = ws + (ch ? OFF_HARMR : OFF_HARML) + (size_t)b*TT*NHARM;
  float tm = (float)m;
  float hsum = 0.0f;
  for (int k=1;k<=NHARM;k++){
    float instf = __fmul_rn(f0u, (float)k);          // RN32(f0_up*k), exact mask
    if (instf < 21600.0f){
      float a0 = ha[i0*NHARM + (k-1)], a1 = ha[i1*NHARM + (k-1)];
      float ak = __fadd_rn(__fmul_rn(a0, w1), __fmul_rn(a1, w));
      float ph = __fmul_rn(c1s[b*32 + (k-1)], tm);   // RN32(c1*t): exact f32 phase
      double rev = (double)ph * 0.15915494309189535; // /(2pi) in f64
      double fr2 = rev - floor(rev);
      float rad = (float)((fr2 - (fr2 >= 0.5 ? 1.0 : 0.0)) * 6.283185307179586);
      float s = sinf(rad);                            // sin(exact f32 phase)
      hsum = __fadd_rn(hsum, __fmul_rn(ak, s));
    }
  }
  float harm = __fmul_rn(hsum, oa);
  // noise OLA gather
  int p = m + 128;
  int fhi = min(p >> 6, NFRAMES-1);
  int flo = max((p - 192) >> 6, 0);
  const float* frb = ws + (ch ? OFF_FRR : OFF_FRL) + (size_t)b*NFRAMES*256;
  float nacc = 0.0f, wsum = 0.0f;
  for (int f=flo; f<=fhi; f++){
    int n = p - f*NHOPF;
    nacc += frb[f*256 + n];
    wsum += win2[n];
  }
  float noise = nacc / fmaxf(wsum, 1e-11f);
  out[idx] = __fadd_rn(harm, noise);
}

extern "C" void kernel_launch(void* const* d_in, const int* in_sizes, int n_in,
                              void* d_out, int out_size, void* d_ws, size_t ws_size,
                              hipStream_t stream){
  const float* f0  = (const float*)d_in[0];
  const float* ldb = (const float*)d_in[1];
  const float* vel = (const float*)d_in[2];
  const float* nL  = (const float*)d_in[3];
  const float* nR  = (const float*)d_in[4];
  const float* Wp1 = (const float*)d_in[5];
  const float* bp1 = (const float*)d_in[6];
  const float* Wp2 = (const float*)d_in[7];
  const float* bp2 = (const float*)d_in[8];
  const float* Wih = (const float*)d_in[9];
  const float* Whh = (const float*)d_in[10];
  const float* bih = (const float*)d_in[11];
  const float* bhh = (const float*)d_in[12];
  const float* Wpo = (const float*)d_in[13];
  const float* bpo = (const float*)d_in[14];
  const float* WhL = (const float*)d_in[15];
  const float* bhL = (const float*)d_in[16];
  const float* WhR = (const float*)d_in[17];
  const float* bhR = (const float*)d_in[18];
  const float* Wam = (const float*)d_in[19];
  const float* bam = (const float*)d_in[20];
  const float* WnL = (const float*)d_in[21];
  const float* bnL = (const float*)d_in[22];
  const float* WnR = (const float*)d_in[23];
  const float* bnR = (const float*)d_in[24];
  float* ws = (float*)d_ws;
  float* out = (float*)d_out;

  k_enc<<<(BB*TT+255)/256, 256, 0, stream>>>(f0, ldb, vel, ws+OFF_FEAT);
  k_mm<1><<<(BB*TT*128+255)/256, 256, 0, stream>>>(ws+OFF_FEAT, Wp1, bp1, ws+OFF_H1, BB*TT, 128, FEATD);
  k_mm<1><<<(BB*TT*128+255)/256, 256, 0, stream>>>(ws+OFF_H1, Wp2, bp2, ws+OFF_H2, BB*TT, 128, 128);
  k_mm<0><<<(BB*TT*192+255)/256, 256, 0, stream>>>(ws+OFF_H2, Wih, bih, ws+OFF_GI, BB*TT, 192, 128);
  k_gru<<<BB, 192, 0, stream>>>(ws+OFF_GI, Whh, bhh, ws+OFF_GOUT);
  k_mm<1><<<(BB*TT*128+255)/256, 256, 0, stream>>>(ws+OFF_GOUT, Wpo, bpo, ws+OFF_POST, BB*TT, 128, HID);
  k_heads<<<(BB*TT*323+255)/256, 256, 0, stream>>>(ws+OFF_POST, WhL,bhL, WhR,bhR, Wam,bam, WnL,bnL, WnR,bnR,
      ws+OFF_HARML, ws+OFF_HARMR, ws+OFF_AMP, ws+OFF_NMAGL, ws+OFF_NMAGR);
  dim3 gmf(BB, 32);
  k_meanf0_np<<<gmf, 256, 0, stream>>>(f0, ws);
  dim3 gs(BB*NFRAMES, 2);
  k_stft<<<gs, 64, 0, stream>>>(nL, nR, ws);
  k_istft<<<gs, 256, 0, stream>>>(ws);
  k_out<<<(BB*2*NSAMP+255)/256, 256, 0, stream>>>(f0, ws, out);
}